// Round 1
// baseline (458.138 us; speedup 1.0000x reference)
//
#include <hip/hip_runtime.h>
#include <hip/hip_bf16.h>
#include <stdint.h>

#define B_ 2
#define T_ 2048
#define D_ 2048
#define H_ 16
#define KVH_ 4
#define DK_ 128

typedef __bf16 bf16x8 __attribute__((ext_vector_type(8)));
typedef float f32x4 __attribute__((ext_vector_type(4)));

typedef __attribute__((address_space(1))) void* gas1_t;
typedef __attribute__((address_space(3))) void* gas3_t;

__device__ __forceinline__ uint16_t f2bf(float f) {
  uint32_t u = __builtin_bit_cast(uint32_t, f);
  u += 0x7FFFu + ((u >> 16) & 1u);
  return (uint16_t)(u >> 16);
}

__device__ __forceinline__ void async16(const void* g, void* l) {
  __builtin_amdgcn_global_load_lds((gas1_t)(uintptr_t)g, (gas3_t)l, 16, 0, 0);
}

// ---------------- fp32 -> bf16 convert ----------------
__global__ __launch_bounds__(256) void k_cvt(const float* __restrict__ s,
                                             uint16_t* __restrict__ d, int n8) {
  int i = blockIdx.x * 256 + threadIdx.x;
  if (i >= n8) return;
  const float4* s4 = (const float4*)s;
  float4 a = s4[(size_t)i * 2], b = s4[(size_t)i * 2 + 1];
  union { uint16_t u[8]; uint4 v; } o;
  o.u[0] = f2bf(a.x); o.u[1] = f2bf(a.y); o.u[2] = f2bf(a.z); o.u[3] = f2bf(a.w);
  o.u[4] = f2bf(b.x); o.u[5] = f2bf(b.y); o.u[6] = f2bf(b.z); o.u[7] = f2bf(b.w);
  ((uint4*)d)[i] = o.v;
}

// ---------------- bf16 GEMM: C(MxN) = A(MxK) * B(NxK)^T, fp32 out ----------------
__global__ __launch_bounds__(256) void k_gemm_bt(const uint16_t* __restrict__ A,
                                                 const uint16_t* __restrict__ Bm,
                                                 float* __restrict__ C,
                                                 int M, int N, int K) {
  __shared__ uint16_t As[128 * 64];
  __shared__ uint16_t Bs[128 * 64];
  const int tid = threadIdx.x;
  const int nt = N >> 7;
  const int m0 = (blockIdx.x / nt) << 7;
  const int n0 = (blockIdx.x % nt) << 7;
  const int w = tid >> 6, lane = tid & 63;
  const int wr = (w >> 1) << 6, wc = (w & 1) << 6;
  const int lr = lane & 15, lk = (lane >> 4) << 3;
  f32x4 acc[4][4] = {};
  const int soff = tid * 16;
  for (int kt = 0; kt < K; kt += 64) {
#pragma unroll
    for (int i = 0; i < 4; ++i) {
      int off = i * 4096 + soff;
      int row = off >> 7;
      int col = (off & 127) >> 1;
      async16(A + (size_t)(m0 + row) * K + kt + col, (char*)As + off);
      async16(Bm + (size_t)(n0 + row) * K + kt + col, (char*)Bs + off);
    }
    __syncthreads();
#pragma unroll
    for (int kk = 0; kk < 64; kk += 32) {
      bf16x8 af[4], bfr[4];
#pragma unroll
      for (int m = 0; m < 4; ++m)
        af[m] = *(const bf16x8*)&As[(wr + m * 16 + lr) * 64 + kk + lk];
#pragma unroll
      for (int n = 0; n < 4; ++n)
        bfr[n] = *(const bf16x8*)&Bs[(wc + n * 16 + lr) * 64 + kk + lk];
#pragma unroll
      for (int m = 0; m < 4; ++m)
#pragma unroll
        for (int n = 0; n < 4; ++n)
          acc[m][n] = __builtin_amdgcn_mfma_f32_16x16x32_bf16(af[m], bfr[n], acc[m][n], 0, 0, 0);
    }
    __syncthreads();
  }
  const int r0 = (lane >> 4) << 2;
  const int c = lane & 15;
#pragma unroll
  for (int m = 0; m < 4; ++m)
#pragma unroll
    for (int n = 0; n < 4; ++n)
#pragma unroll
      for (int r = 0; r < 4; ++r)
        C[(size_t)(m0 + wr + m * 16 + r0 + r) * N + n0 + wc + n * 16 + c] = acc[m][n][r];
}

// ---------------- l2norm (+ optional gain) -> bf16, head-major out ----------------
// P: (B*T, NH*128) fp32.  Out: (B, NH, T, 128) bf16.  One wave per (row, h).
__global__ __launch_bounds__(256) void k_qknorm(const float* __restrict__ P,
                                                uint16_t* __restrict__ Out,
                                                const float* __restrict__ g,
                                                int NH, int useg) {
  int gw = blockIdx.x * 4 + (threadIdx.x >> 6);
  int lane = threadIdx.x & 63;
  int h = gw % NH;
  int row = gw / NH;          // b*T + t
  int b = row >> 11;
  int t = row & (T_ - 1);
  const float* src = P + (size_t)row * (NH * 128) + h * 128 + lane * 2;
  float2 xy = *(const float2*)src;
  float ss = xy.x * xy.x + xy.y * xy.y;
#pragma unroll
  for (int s = 32; s > 0; s >>= 1) ss += __shfl_xor(ss, s);
  float nrm = fmaxf(sqrtf(ss), 1e-12f);
  float scl = (useg ? g[h] * 0.08838834764831845f : 1.0f) / nrm;  // fold 1/sqrt(128) into Q
  uint32_t pk = (uint32_t)f2bf(xy.x * scl) | ((uint32_t)f2bf(xy.y * scl) << 16);
  uint32_t* dst = (uint32_t*)(Out + ((size_t)(b * NH + h) * T_ + t) * 128) + lane;
  *dst = pk;
}

// ---------------- V: (B*T, KVH*128) fp32 -> Vt (B, KVH, 128, T) bf16 ----------------
__global__ __launch_bounds__(256) void k_vtrans(const float* __restrict__ P,
                                                uint16_t* __restrict__ Vt) {
  __shared__ uint16_t ls[128][65];
  int bx = blockIdx.x;
  int tt = bx & 31;
  int kvh = (bx >> 5) & 3;
  int b = bx >> 7;
  int t0 = tt << 6;
  int tid = threadIdx.x;
#pragma unroll
  for (int i = 0; i < 8; ++i) {
    int chunk = i * 256 + tid;          // 0..2047
    int trow = chunk >> 5;
    int c4 = (chunk & 31) << 2;
    float4 v = *(const float4*)(P + (size_t)(b * T_ + t0 + trow) * (KVH_ * 128) + kvh * 128 + c4);
    ls[c4 + 0][trow] = f2bf(v.x);
    ls[c4 + 1][trow] = f2bf(v.y);
    ls[c4 + 2][trow] = f2bf(v.z);
    ls[c4 + 3][trow] = f2bf(v.w);
  }
  __syncthreads();
  int d = tid >> 1, half = tid & 1;
  uint16_t* dst = Vt + ((size_t)(b * KVH_ + kvh) * 128 + d) * T_ + t0 + half * 32;
  const uint16_t* srcl = &ls[d][half * 32];
#pragma unroll
  for (int j = 0; j < 32; ++j) dst[j] = srcl[j];
}

// ---------------- causal GQA flash attention ----------------
// Qn: (B,H,T,128) bf16 pre-scaled by g/sqrt(dk); Kn: (B,KVH,T,128); Vt: (B,KVH,128,T)
// Y out: (B,T,H*128) bf16.  Scores bounded by ~0.68 -> no max subtraction needed.
__global__ __launch_bounds__(256) void k_attn(const uint16_t* __restrict__ Qn,
                                              const uint16_t* __restrict__ Kn,
                                              const uint16_t* __restrict__ Vt,
                                              uint16_t* __restrict__ Y) {
  __shared__ uint16_t Ks[64 * 128];
  __shared__ uint16_t Vs[128 * 64];
  __shared__ uint16_t Ps[4 * 16 * 32];
  const int nq = T_ / 64;
  const int qt = blockIdx.x % nq;
  const int bh = blockIdx.x / nq;
  const int h = bh % H_;
  const int b = bh / H_;
  const int kvh = h >> 2;
  const uint16_t* Qh = Qn + ((size_t)(b * H_ + h) * T_) * 128;
  const uint16_t* Kh = Kn + ((size_t)(b * KVH_ + kvh) * T_) * 128;
  const uint16_t* Vh = Vt + ((size_t)(b * KVH_ + kvh) * 128) * T_;
  const int tid = threadIdx.x;
  const int w = tid >> 6, lane = tid & 63;
  const int lr = lane & 15, lk = (lane >> 4) << 3;
  const int r0 = (lane >> 4) << 2;
  const int q0 = qt * 64;
  const int qw = q0 + w * 16;
  bf16x8 qf[4];
#pragma unroll
  for (int dblk = 0; dblk < 4; ++dblk)
    qf[dblk] = *(const bf16x8*)&Qh[(size_t)(qw + lr) * 128 + dblk * 32 + lk];
  union { uint16_t u[8]; bf16x8 v; } ou;
#pragma unroll
  for (int j = 0; j < 8; ++j) ou.u[j] = 0x3F80;  // bf16(1.0)
  const bf16x8 ones = ou.v;
  f32x4 o[8] = {};
  f32x4 sum = {};
  const int ntiles = qt + 1;
  for (int tile = 0; tile < ntiles; ++tile) {
    const int kv0 = tile * 64;
#pragma unroll
    for (int i = 0; i < 4; ++i) {
      int off = i * 4096 + tid * 16;
      int krow = off >> 8;
      int kcol = (off & 255) >> 1;
      async16(Kh + (size_t)(kv0 + krow) * 128 + kcol, (char*)Ks + off);
      int vrow = off >> 7;
      int vcol = (off & 127) >> 1;
      async16(Vh + (size_t)vrow * T_ + kv0 + vcol, (char*)Vs + off);
    }
    __syncthreads();
#pragma unroll
    for (int pair = 0; pair < 2; ++pair) {
#pragma unroll
      for (int kbi = 0; kbi < 2; ++kbi) {
        int kb = pair * 2 + kbi;
        f32x4 s = {};
#pragma unroll
        for (int dblk = 0; dblk < 4; ++dblk) {
          bf16x8 kf = *(const bf16x8*)&Ks[(kb * 16 + lr) * 128 + dblk * 32 + lk];
          s = __builtin_amdgcn_mfma_f32_16x16x32_bf16(qf[dblk], kf, s, 0, 0, 0);
        }
        int kval = kv0 + kb * 16 + lr;   // C/D col = lane&15 = k index
#pragma unroll
        for (int r = 0; r < 4; ++r) {
          float pv = (kval <= qw + r0 + r) ? __expf(s[r]) : 0.0f;
          Ps[w * 512 + (r0 + r) * 32 + kbi * 16 + lr] = f2bf(pv);
        }
      }
      asm volatile("s_waitcnt lgkmcnt(0)" ::: "memory");
      bf16x8 pa = *(const bf16x8*)&Ps[w * 512 + lr * 32 + lk];
#pragma unroll
      for (int dblk = 0; dblk < 8; ++dblk) {
        bf16x8 vf = *(const bf16x8*)&Vs[(dblk * 16 + lr) * 64 + pair * 32 + lk];
        o[dblk] = __builtin_amdgcn_mfma_f32_16x16x32_bf16(pa, vf, o[dblk], 0, 0, 0);
      }
      sum = __builtin_amdgcn_mfma_f32_16x16x32_bf16(pa, ones, sum, 0, 0, 0);
    }
    __syncthreads();
  }
#pragma unroll
  for (int dblk = 0; dblk < 8; ++dblk)
#pragma unroll
    for (int r = 0; r < 4; ++r) {
      float y = o[dblk][r] / sum[r];
      size_t qidx = (size_t)(qw + r0 + r);
      Y[((size_t)b * T_ + qidx) * D_ + h * 128 + dblk * 16 + lr] = f2bf(y);
    }
}

extern "C" void kernel_launch(void* const* d_in, const int* in_sizes, int n_in,
                              void* d_out, int out_size, void* d_ws, size_t ws_size,
                              hipStream_t stream) {
  (void)in_sizes; (void)n_in; (void)out_size; (void)ws_size;
  const float* q  = (const float*)d_in[0];
  const float* k  = (const float*)d_in[1];
  const float* v  = (const float*)d_in[2];
  const float* Wq = (const float*)d_in[3];
  const float* Wk = (const float*)d_in[4];
  const float* Wv = (const float*)d_in[5];
  const float* Wo = (const float*)d_in[6];
  const float* g  = (const float*)d_in[7];
  float* out = (float*)d_out;
  char* ws = (char*)d_ws;
  uint16_t* actA = (uint16_t*)(ws);                       // 16 MB (qb/kb/vb/Y)
  uint16_t* Wb   = (uint16_t*)(ws + (16ull << 20));       // 8 MB
  float*    Pp   = (float*)   (ws + (24ull << 20));       // 32 MB
  uint16_t* Qn   = (uint16_t*)(ws + (56ull << 20));       // 16 MB
  uint16_t* Kn   = (uint16_t*)(ws + (72ull << 20));       // 4 MB
  uint16_t* Vtb  = (uint16_t*)(ws + (76ull << 20));       // 4 MB

  auto cvt = [&](const float* src, uint16_t* dst, int n) {
    int n8 = n / 8;
    k_cvt<<<(n8 + 255) / 256, 256, 0, stream>>>(src, dst, n8);
  };
  const int MBT = B_ * T_;  // 4096

  // Q path
  cvt(q, actA, MBT * D_);
  cvt(Wq, Wb, D_ * D_);
  k_gemm_bt<<<(MBT / 128) * (D_ / 128), 256, 0, stream>>>(actA, Wb, Pp, MBT, D_, D_);
  k_qknorm<<<(MBT * H_) / 4, 256, 0, stream>>>(Pp, Qn, g, H_, 1);
  // K path
  cvt(k, actA, MBT * D_);
  cvt(Wk, Wb, KVH_ * DK_ * D_);
  k_gemm_bt<<<(MBT / 128) * ((KVH_ * DK_) / 128), 256, 0, stream>>>(actA, Wb, Pp, MBT, KVH_ * DK_, D_);
  k_qknorm<<<(MBT * KVH_) / 4, 256, 0, stream>>>(Pp, Kn, g, KVH_, 0);
  // V path
  cvt(v, actA, MBT * D_);
  cvt(Wv, Wb, KVH_ * DK_ * D_);
  k_gemm_bt<<<(MBT / 128) * ((KVH_ * DK_) / 128), 256, 0, stream>>>(actA, Wb, Pp, MBT, KVH_ * DK_, D_);
  k_vtrans<<<B_ * KVH_ * (T_ / 64), 256, 0, stream>>>(Pp, Vtb);
  // attention
  k_attn<<<B_ * H_ * (T_ / 64), 256, 0, stream>>>(Qn, Kn, Vtb, actA);
  // output projection
  cvt(Wo, Wb, D_ * D_);
  k_gemm_bt<<<(MBT / 128) * (D_ / 128), 256, 0, stream>>>(actA, Wb, out, MBT, D_, D_);
}

// Round 2
// 313.093 us; speedup vs baseline: 1.4633x; 1.4633x over previous
//
#include <hip/hip_runtime.h>
#include <hip/hip_bf16.h>
#include <stdint.h>

#define B_ 2
#define T_ 2048
#define D_ 2048
#define H_ 16
#define KVH_ 4
#define DK_ 128

typedef __bf16 bf16x8 __attribute__((ext_vector_type(8)));
typedef float f32x4 __attribute__((ext_vector_type(4)));

typedef __attribute__((address_space(1))) void* gas1_t;
typedef __attribute__((address_space(3))) void* gas3_t;

__device__ __forceinline__ uint16_t f2bf(float f) {
  uint32_t u = __builtin_bit_cast(uint32_t, f);
  u += 0x7FFFu + ((u >> 16) & 1u);
  return (uint16_t)(u >> 16);
}

__device__ __forceinline__ void async16(const void* g, void* l) {
  __builtin_amdgcn_global_load_lds((gas1_t)(uintptr_t)g, (gas3_t)l, 16, 0, 0);
}

// ---------------- fp32 -> bf16 convert ----------------
__global__ __launch_bounds__(256) void k_cvt(const float* __restrict__ s,
                                             uint16_t* __restrict__ d, int n8) {
  int i = blockIdx.x * 256 + threadIdx.x;
  if (i >= n8) return;
  const float4* s4 = (const float4*)s;
  float4 a = s4[(size_t)i * 2], b = s4[(size_t)i * 2 + 1];
  union { uint16_t u[8]; uint4 v; } o;
  o.u[0] = f2bf(a.x); o.u[1] = f2bf(a.y); o.u[2] = f2bf(a.z); o.u[3] = f2bf(a.w);
  o.u[4] = f2bf(b.x); o.u[5] = f2bf(b.y); o.u[6] = f2bf(b.z); o.u[7] = f2bf(b.w);
  ((uint4*)d)[i] = o.v;
}

// ---------------- bf16 GEMM: C(MxN) = A(MxK) * B(NxK)^T, fp32 out ----------------
__global__ __launch_bounds__(256) void k_gemm_bt(const uint16_t* __restrict__ A,
                                                 const uint16_t* __restrict__ Bm,
                                                 float* __restrict__ C,
                                                 int M, int N, int K) {
  __shared__ uint16_t As[128 * 64];
  __shared__ uint16_t Bs[128 * 64];
  const int tid = threadIdx.x;
  const int nt = N >> 7;
  const int m0 = (blockIdx.x / nt) << 7;
  const int n0 = (blockIdx.x % nt) << 7;
  const int w = tid >> 6, lane = tid & 63;
  const int wr = (w >> 1) << 6, wc = (w & 1) << 6;
  const int lr = lane & 15, lk = (lane >> 4) << 3;
  f32x4 acc[4][4] = {};
  const int soff = tid * 16;
  for (int kt = 0; kt < K; kt += 64) {
#pragma unroll
    for (int i = 0; i < 4; ++i) {
      int off = i * 4096 + soff;
      int row = off >> 7;
      int col = (off & 127) >> 1;
      async16(A + (size_t)(m0 + row) * K + kt + col, (char*)As + off);
      async16(Bm + (size_t)(n0 + row) * K + kt + col, (char*)Bs + off);
    }
    __syncthreads();
#pragma unroll
    for (int kk = 0; kk < 64; kk += 32) {
      bf16x8 af[4], bfr[4];
#pragma unroll
      for (int m = 0; m < 4; ++m)
        af[m] = *(const bf16x8*)&As[(wr + m * 16 + lr) * 64 + kk + lk];
#pragma unroll
      for (int n = 0; n < 4; ++n)
        bfr[n] = *(const bf16x8*)&Bs[(wc + n * 16 + lr) * 64 + kk + lk];
#pragma unroll
      for (int m = 0; m < 4; ++m)
#pragma unroll
        for (int n = 0; n < 4; ++n)
          acc[m][n] = __builtin_amdgcn_mfma_f32_16x16x32_bf16(af[m], bfr[n], acc[m][n], 0, 0, 0);
    }
    __syncthreads();
  }
  const int r0 = (lane >> 4) << 2;
  const int c = lane & 15;
#pragma unroll
  for (int m = 0; m < 4; ++m)
#pragma unroll
    for (int n = 0; n < 4; ++n)
#pragma unroll
      for (int r = 0; r < 4; ++r)
        C[(size_t)(m0 + wr + m * 16 + r0 + r) * N + n0 + wc + n * 16 + c] = acc[m][n][r];
}

// ---------------- l2norm (+ optional gain) -> bf16, head-major out ----------------
__global__ __launch_bounds__(256) void k_qknorm(const float* __restrict__ P,
                                                uint16_t* __restrict__ Out,
                                                const float* __restrict__ g,
                                                int NH, int useg) {
  int gw = blockIdx.x * 4 + (threadIdx.x >> 6);
  int lane = threadIdx.x & 63;
  int h = gw % NH;
  int row = gw / NH;          // b*T + t
  int b = row >> 11;
  int t = row & (T_ - 1);
  const float* src = P + (size_t)row * (NH * 128) + h * 128 + lane * 2;
  float2 xy = *(const float2*)src;
  float ss = xy.x * xy.x + xy.y * xy.y;
#pragma unroll
  for (int s = 32; s > 0; s >>= 1) ss += __shfl_xor(ss, s);
  float nrm = fmaxf(sqrtf(ss), 1e-12f);
  float scl = (useg ? g[h] * 0.08838834764831845f : 1.0f) / nrm;  // fold 1/sqrt(128) into Q
  uint32_t pk = (uint32_t)f2bf(xy.x * scl) | ((uint32_t)f2bf(xy.y * scl) << 16);
  uint32_t* dst = (uint32_t*)(Out + ((size_t)(b * NH + h) * T_ + t) * 128) + lane;
  *dst = pk;
}

// ---------------- V: (B*T, KVH*128) fp32 -> Vt (B, KVH, 128, T) bf16 ----------------
__global__ __launch_bounds__(256) void k_vtrans(const float* __restrict__ P,
                                                uint16_t* __restrict__ Vt) {
  __shared__ uint16_t ls[128][65];
  int bx = blockIdx.x;
  int tt = bx & 31;
  int kvh = (bx >> 5) & 3;
  int b = bx >> 7;
  int t0 = tt << 6;
  int tid = threadIdx.x;
#pragma unroll
  for (int i = 0; i < 8; ++i) {
    int chunk = i * 256 + tid;          // 0..2047
    int trow = chunk >> 5;
    int c4 = (chunk & 31) << 2;
    float4 v = *(const float4*)(P + (size_t)(b * T_ + t0 + trow) * (KVH_ * 128) + kvh * 128 + c4);
    ls[c4 + 0][trow] = f2bf(v.x);
    ls[c4 + 1][trow] = f2bf(v.y);
    ls[c4 + 2][trow] = f2bf(v.z);
    ls[c4 + 3][trow] = f2bf(v.w);
  }
  __syncthreads();
  int d = tid >> 1, half = tid & 1;
  uint16_t* dst = Vt + ((size_t)(b * KVH_ + kvh) * 128 + d) * T_ + t0 + half * 32;
  const uint16_t* srcl = &ls[d][half * 32];
#pragma unroll
  for (int j = 0; j < 32; ++j) dst[j] = srcl[j];
}

// ---------------- causal GQA flash attention, paired q-tiles ----------------
// Qn: (B,H,T,128) bf16 pre-scaled by g/sqrt(dk); Kn: (B,KVH,T,128); Vt: (B,KVH,128,T)
// Y out: (B,T,H*128) bf16.  Scores bounded -> plain exp, no max subtraction.
// Block handles q-tiles {p, 31-p}: uniform 33 tile-computes/block, shared K/V staging.
// K/V LDS XOR-swizzled (byte ^= (row&7)<<4) via pre-swizzled global_load_lds source.
__global__ __launch_bounds__(256) void k_attn(const uint16_t* __restrict__ Qn,
                                              const uint16_t* __restrict__ Kn,
                                              const uint16_t* __restrict__ Vt,
                                              uint16_t* __restrict__ Y) {
  __shared__ uint16_t Ks[64 * 128];
  __shared__ uint16_t Vs[128 * 64];
  __shared__ uint16_t Ps[4 * 16 * 32];
  const int npair = T_ / 128;              // 16
  const int pair_id = blockIdx.x % npair;
  const int bh = blockIdx.x / npair;
  const int h = bh % H_;
  const int b = bh / H_;
  const int kvh = h >> 2;
  const int qtA = pair_id;                 // light tile
  const int qtB = (T_ / 64) - 1 - pair_id; // heavy tile
  const uint16_t* Qh = Qn + ((size_t)(b * H_ + h) * T_) * 128;
  const uint16_t* Kh = Kn + ((size_t)(b * KVH_ + kvh) * T_) * 128;
  const uint16_t* Vh = Vt + ((size_t)(b * KVH_ + kvh) * 128) * T_;
  const int tid = threadIdx.x;
  const int w = tid >> 6, lane = tid & 63;
  const int lr = lane & 15;
  const int lk2 = (lane >> 4) << 4;        // byte offset of k-slice within row
  const int r0 = (lane >> 4) << 2;
  const int qwA = qtA * 64 + w * 16;
  const int qwB = qtB * 64 + w * 16;
  char* Psw = (char*)Ps + w * 1024;

  bf16x8 qfA[4], qfB[4];
#pragma unroll
  for (int dblk = 0; dblk < 4; ++dblk) {
    qfA[dblk] = *(const bf16x8*)&Qh[(size_t)(qwA + lr) * 128 + dblk * 32 + (lk2 >> 1)];
    qfB[dblk] = *(const bf16x8*)&Qh[(size_t)(qwB + lr) * 128 + dblk * 32 + (lk2 >> 1)];
  }
  union { uint16_t u[8]; bf16x8 v; } ou;
#pragma unroll
  for (int j = 0; j < 8; ++j) ou.u[j] = 0x3F80;  // bf16(1.0)
  const bf16x8 ones = ou.v;
  f32x4 oA[8] = {}, oB[8] = {};
  f32x4 sumA = {}, sumB = {};

  auto tilecompute = [&](const bf16x8* qf, f32x4* o, f32x4* sum, int qw, int kv0) {
#pragma unroll
    for (int prr = 0; prr < 2; ++prr) {
#pragma unroll
      for (int kbi = 0; kbi < 2; ++kbi) {
        int kb = prr * 2 + kbi;
        f32x4 s = {};
#pragma unroll
        for (int dblk = 0; dblk < 4; ++dblk) {
          bf16x8 kf = *(const bf16x8*)((const char*)Ks +
              ((kb * 16 + lr) << 8) + ((dblk * 64 + lk2) ^ ((lr & 7) << 4)));
          s = __builtin_amdgcn_mfma_f32_16x16x32_bf16(qf[dblk], kf, s, 0, 0, 0);
        }
        int kval = kv0 + kb * 16 + lr;   // C/D col = lane&15 = k index
#pragma unroll
        for (int r = 0; r < 4; ++r) {
          float pv = (kval <= qw + r0 + r) ? __expf(s[r]) : 0.0f;
          *(uint16_t*)(Psw + (r0 + r) * 64 + (((kbi * 16 + lr) * 2) ^ (r << 4))) = f2bf(pv);
        }
      }
      asm volatile("s_waitcnt lgkmcnt(0)" ::: "memory");
      bf16x8 pa = *(const bf16x8*)(Psw + lr * 64 + (lk2 ^ ((lr & 3) << 4)));
#pragma unroll
      for (int dblk = 0; dblk < 8; ++dblk) {
        bf16x8 vf = *(const bf16x8*)((const char*)Vs +
            ((dblk * 16 + lr) << 7) + ((prr * 64 + lk2) ^ ((lr & 7) << 4)));
        o[dblk] = __builtin_amdgcn_mfma_f32_16x16x32_bf16(pa, vf, o[dblk], 0, 0, 0);
      }
      *sum = __builtin_amdgcn_mfma_f32_16x16x32_bf16(pa, ones, *sum, 0, 0, 0);
    }
  };

  for (int tile = 0; tile <= qtB; ++tile) {
    const int kv0 = tile * 64;
#pragma unroll
    for (int i = 0; i < 4; ++i) {
      int off = i * 4096 + tid * 16;
      // K: logical row stride 256B, storage chunk = logical chunk ^ (row&7)
      int krow = off >> 8;
      int kchunk = (off >> 4) & 15;
      int kcol = (kchunk ^ (krow & 7)) << 3;
      async16(Kh + (size_t)(kv0 + krow) * 128 + kcol, (char*)Ks + off);
      // V: logical row stride 128B
      int vrow = off >> 7;
      int vchunk = (off >> 4) & 7;
      int vcol = (vchunk ^ (vrow & 7)) << 3;
      async16(Vh + (size_t)vrow * T_ + kv0 + vcol, (char*)Vs + off);
    }
    __syncthreads();
    tilecompute(qfB, oB, &sumB, qwB, kv0);
    if (tile <= qtA) tilecompute(qfA, oA, &sumA, qwA, kv0);
    __syncthreads();
  }

  auto writeout = [&](const f32x4* o, const f32x4& sum, int qw) {
#pragma unroll
    for (int r = 0; r < 4; ++r) {
      float inv = 1.0f / sum[r];
      size_t base = ((size_t)b * T_ + (qw + r0 + r)) * D_ + h * 128 + lr;
#pragma unroll
      for (int dblk = 0; dblk < 8; ++dblk)
        Y[base + dblk * 16] = f2bf(o[dblk][r] * inv);
    }
  };
  writeout(oA, sumA, qwA);
  writeout(oB, sumB, qwB);
}

extern "C" void kernel_launch(void* const* d_in, const int* in_sizes, int n_in,
                              void* d_out, int out_size, void* d_ws, size_t ws_size,
                              hipStream_t stream) {
  (void)in_sizes; (void)n_in; (void)out_size; (void)ws_size;
  const float* q  = (const float*)d_in[0];
  const float* k  = (const float*)d_in[1];
  const float* v  = (const float*)d_in[2];
  const float* Wq = (const float*)d_in[3];
  const float* Wk = (const float*)d_in[4];
  const float* Wv = (const float*)d_in[5];
  const float* Wo = (const float*)d_in[6];
  const float* g  = (const float*)d_in[7];
  float* out = (float*)d_out;
  char* ws = (char*)d_ws;
  uint16_t* actA = (uint16_t*)(ws);                       // 16 MB (qb/kb/vb/Y)
  uint16_t* Wb   = (uint16_t*)(ws + (16ull << 20));       // 8 MB
  float*    Pp   = (float*)   (ws + (24ull << 20));       // 32 MB
  uint16_t* Qn   = (uint16_t*)(ws + (56ull << 20));       // 16 MB
  uint16_t* Kn   = (uint16_t*)(ws + (72ull << 20));       // 4 MB
  uint16_t* Vtb  = (uint16_t*)(ws + (76ull << 20));       // 4 MB

  auto cvt = [&](const float* src, uint16_t* dst, int n) {
    int n8 = n / 8;
    k_cvt<<<(n8 + 255) / 256, 256, 0, stream>>>(src, dst, n8);
  };
  const int MBT = B_ * T_;  // 4096

  // Q path
  cvt(q, actA, MBT * D_);
  cvt(Wq, Wb, D_ * D_);
  k_gemm_bt<<<(MBT / 128) * (D_ / 128), 256, 0, stream>>>(actA, Wb, Pp, MBT, D_, D_);
  k_qknorm<<<(MBT * H_) / 4, 256, 0, stream>>>(Pp, Qn, g, H_, 1);
  // K path
  cvt(k, actA, MBT * D_);
  cvt(Wk, Wb, KVH_ * DK_ * D_);
  k_gemm_bt<<<(MBT / 128) * ((KVH_ * DK_) / 128), 256, 0, stream>>>(actA, Wb, Pp, MBT, KVH_ * DK_, D_);
  k_qknorm<<<(MBT * KVH_) / 4, 256, 0, stream>>>(Pp, Kn, g, KVH_, 0);
  // V path
  cvt(v, actA, MBT * D_);
  cvt(Wv, Wb, KVH_ * DK_ * D_);
  k_gemm_bt<<<(MBT / 128) * ((KVH_ * DK_) / 128), 256, 0, stream>>>(actA, Wb, Pp, MBT, KVH_ * DK_, D_);
  k_vtrans<<<B_ * KVH_ * (T_ / 64), 256, 0, stream>>>(Pp, Vtb);
  // attention
  k_attn<<<B_ * H_ * (T_ / 128), 256, 0, stream>>>(Qn, Kn, Vtb, actA);
  // output projection
  cvt(Wo, Wb, D_ * D_);
  k_gemm_bt<<<(MBT / 128) * (D_ / 128), 256, 0, stream>>>(actA, Wb, out, MBT, D_, D_);
}

// Round 4
// 241.535 us; speedup vs baseline: 1.8968x; 1.2963x over previous
//
#include <hip/hip_runtime.h>
#include <hip/hip_bf16.h>
#include <stdint.h>

#define B_ 2
#define T_ 2048
#define D_ 2048
#define H_ 16
#define KVH_ 4
#define DK_ 128

typedef __bf16 bf16x8 __attribute__((ext_vector_type(8)));
typedef float f32x4 __attribute__((ext_vector_type(4)));

typedef __attribute__((address_space(1))) void* gas1_t;
typedef __attribute__((address_space(3))) void* gas3_t;

__device__ __forceinline__ uint16_t f2bf(float f) {
  uint32_t u = __builtin_bit_cast(uint32_t, f);
  u += 0x7FFFu + ((u >> 16) & 1u);
  return (uint16_t)(u >> 16);
}

__device__ __forceinline__ void async16(const void* g, void* l) {
  __builtin_amdgcn_global_load_lds((gas1_t)(uintptr_t)g, (gas3_t)l, 16, 0, 0);
}

// ---------------- fp32 -> bf16 convert (single buffer) ----------------
__global__ __launch_bounds__(256) void k_cvt(const float* __restrict__ s,
                                             uint16_t* __restrict__ d, int n8) {
  int i = blockIdx.x * 256 + threadIdx.x;
  if (i >= n8) return;
  const float4* s4 = (const float4*)s;
  float4 a = s4[(size_t)i * 2], b = s4[(size_t)i * 2 + 1];
  union { uint16_t u[8]; uint4 v; } o;
  o.u[0] = f2bf(a.x); o.u[1] = f2bf(a.y); o.u[2] = f2bf(a.z); o.u[3] = f2bf(a.w);
  o.u[4] = f2bf(b.x); o.u[5] = f2bf(b.y); o.u[6] = f2bf(b.z); o.u[7] = f2bf(b.w);
  ((uint4*)d)[i] = o.v;
}

// ---------------- all-inputs fp32 -> bf16 convert, one launch ----------------
// segments (in blocks of 256 thr x 8 elem): q 4096, k 4096, v 4096, Wq 2048, Wk 512, Wv 512
__global__ __launch_bounds__(256) void k_cvt_all(const float* __restrict__ q,
                                                 const float* __restrict__ k,
                                                 const float* __restrict__ v,
                                                 const float* __restrict__ wq,
                                                 const float* __restrict__ wk,
                                                 const float* __restrict__ wv,
                                                 uint16_t* __restrict__ qb,
                                                 uint16_t* __restrict__ kb,
                                                 uint16_t* __restrict__ vb,
                                                 uint16_t* __restrict__ wqb,
                                                 uint16_t* __restrict__ wkb,
                                                 uint16_t* __restrict__ wvb) {
  int gb = blockIdx.x;
  const float* s; uint16_t* d; int base;
  if (gb < 4096)        { s = q;  d = qb;  base = 0; }
  else if (gb < 8192)   { s = k;  d = kb;  base = 4096; }
  else if (gb < 12288)  { s = v;  d = vb;  base = 8192; }
  else if (gb < 14336)  { s = wq; d = wqb; base = 12288; }
  else if (gb < 14848)  { s = wk; d = wkb; base = 14336; }
  else                  { s = wv; d = wvb; base = 14848; }
  int i = (gb - base) * 256 + threadIdx.x;
  const float4* s4 = (const float4*)s;
  float4 a = s4[(size_t)i * 2], b = s4[(size_t)i * 2 + 1];
  union { uint16_t u[8]; uint4 v; } o;
  o.u[0] = f2bf(a.x); o.u[1] = f2bf(a.y); o.u[2] = f2bf(a.z); o.u[3] = f2bf(a.w);
  o.u[4] = f2bf(b.x); o.u[5] = f2bf(b.y); o.u[6] = f2bf(b.z); o.u[7] = f2bf(b.w);
  ((uint4*)d)[i] = o.v;
}

// ---------------- bf16 GEMM: C(MxN) = A(MxK) * B(NxK)^T, fp32 out ----------------
__global__ __launch_bounds__(256) void k_gemm_bt(const uint16_t* __restrict__ A,
                                                 const uint16_t* __restrict__ Bm,
                                                 float* __restrict__ C,
                                                 int M, int N, int K) {
  __shared__ uint16_t As[128 * 64];
  __shared__ uint16_t Bs[128 * 64];
  const int tid = threadIdx.x;
  const int nt = N >> 7;
  const int m0 = (blockIdx.x / nt) << 7;
  const int n0 = (blockIdx.x % nt) << 7;
  const int w = tid >> 6, lane = tid & 63;
  const int wr = (w >> 1) << 6, wc = (w & 1) << 6;
  const int lr = lane & 15, lk = (lane >> 4) << 3;
  f32x4 acc[4][4] = {};
  const int soff = tid * 16;
  for (int kt = 0; kt < K; kt += 64) {
#pragma unroll
    for (int i = 0; i < 4; ++i) {
      int off = i * 4096 + soff;
      int row = off >> 7;
      int col = (off & 127) >> 1;
      async16(A + (size_t)(m0 + row) * K + kt + col, (char*)As + off);
      async16(Bm + (size_t)(n0 + row) * K + kt + col, (char*)Bs + off);
    }
    __syncthreads();
#pragma unroll
    for (int kk = 0; kk < 64; kk += 32) {
      bf16x8 af[4], bfr[4];
#pragma unroll
      for (int m = 0; m < 4; ++m)
        af[m] = *(const bf16x8*)&As[(wr + m * 16 + lr) * 64 + kk + lk];
#pragma unroll
      for (int n = 0; n < 4; ++n)
        bfr[n] = *(const bf16x8*)&Bs[(wc + n * 16 + lr) * 64 + kk + lk];
#pragma unroll
      for (int m = 0; m < 4; ++m)
#pragma unroll
        for (int n = 0; n < 4; ++n)
          acc[m][n] = __builtin_amdgcn_mfma_f32_16x16x32_bf16(af[m], bfr[n], acc[m][n], 0, 0, 0);
    }
    __syncthreads();
  }
  const int r0 = (lane >> 4) << 2;
  const int c = lane & 15;
#pragma unroll
  for (int m = 0; m < 4; ++m)
#pragma unroll
    for (int n = 0; n < 4; ++n)
#pragma unroll
      for (int r = 0; r < 4; ++r)
        C[(size_t)(m0 + wr + m * 16 + r0 + r) * N + n0 + wc + n * 16 + c] = acc[m][n][r];
}

// ---------------- merged QKV projection with fused epilogues ----------------
// Blocks [0,512): Q proj (nt=16) -> l2norm*g/sqrt(dk) -> Qn (B,H,T,128) bf16
// Blocks [512,640): K proj (nt=4) -> l2norm -> Kn (B,KVH,T,128) bf16
// Blocks [640,768): V proj (nt=4) -> transpose -> Vt (B,KVH,128,T) bf16
__global__ __launch_bounds__(256) void k_proj(const uint16_t* __restrict__ qb,
                                              const uint16_t* __restrict__ kb,
                                              const uint16_t* __restrict__ vb,
                                              const uint16_t* __restrict__ Wqb,
                                              const uint16_t* __restrict__ Wkb,
                                              const uint16_t* __restrict__ Wvb,
                                              uint16_t* __restrict__ Qn,
                                              uint16_t* __restrict__ Kn,
                                              uint16_t* __restrict__ Vt,
                                              const float* __restrict__ g) {
  __shared__ uint16_t smem[16896];       // As(8192) + Bs(8192) elems; aliased as tr[128][132]
  __shared__ float ssred[2][128];
  uint16_t* As = smem;
  uint16_t* Bs = smem + 8192;
  const int bid = blockIdx.x;
  int mode, lb;
  if (bid < 512)      { mode = 0; lb = bid; }
  else if (bid < 640) { mode = 1; lb = bid - 512; }
  else                { mode = 2; lb = bid - 640; }
  const uint16_t* A;
  const uint16_t* Bw;
  int nt;
  if (mode == 0)      { A = qb; Bw = Wqb; nt = 16; }
  else if (mode == 1) { A = kb; Bw = Wkb; nt = 4; }
  else                { A = vb; Bw = Wvb; nt = 4; }
  const int K = 2048;
  const int m0 = (lb / nt) << 7;
  const int n0 = (lb % nt) << 7;
  const int tid = threadIdx.x;
  const int w = tid >> 6, lane = tid & 63;
  const int wr = (w >> 1) << 6, wc = (w & 1) << 6;
  const int lr = lane & 15, lk = (lane >> 4) << 3;
  f32x4 acc[4][4] = {};
  const int soff = tid * 16;
  for (int kt = 0; kt < K; kt += 64) {
#pragma unroll
    for (int i = 0; i < 4; ++i) {
      int off = i * 4096 + soff;
      int row = off >> 7;
      int col = (off & 127) >> 1;
      async16(A + (size_t)(m0 + row) * K + kt + col, (char*)As + off);
      async16(Bw + (size_t)(n0 + row) * K + kt + col, (char*)Bs + off);
    }
    __syncthreads();
#pragma unroll
    for (int kk = 0; kk < 64; kk += 32) {
      bf16x8 af[4], bfr[4];
#pragma unroll
      for (int m = 0; m < 4; ++m)
        af[m] = *(const bf16x8*)&As[(wr + m * 16 + lr) * 64 + kk + lk];
#pragma unroll
      for (int n = 0; n < 4; ++n)
        bfr[n] = *(const bf16x8*)&Bs[(wc + n * 16 + lr) * 64 + kk + lk];
#pragma unroll
      for (int m = 0; m < 4; ++m)
#pragma unroll
        for (int n = 0; n < 4; ++n)
          acc[m][n] = __builtin_amdgcn_mfma_f32_16x16x32_bf16(af[m], bfr[n], acc[m][n], 0, 0, 0);
    }
    __syncthreads();
  }
  const int g4 = lane >> 4;
  const int r04 = g4 << 2;
  const int b = m0 >> 11;
  const int t0 = m0 & (T_ - 1);
  const int h = n0 >> 7;

  if (mode <= 1) {
    // ---- fused l2norm epilogue: rows are complete head vectors (BN=128=DK) ----
    float ss[4][4];
#pragma unroll
    for (int m = 0; m < 4; ++m)
#pragma unroll
      for (int r = 0; r < 4; ++r) {
        float s = 0.f;
#pragma unroll
        for (int n = 0; n < 4; ++n) s += acc[m][n][r] * acc[m][n][r];
        ss[m][r] = s;
      }
#pragma unroll
    for (int mask = 1; mask < 16; mask <<= 1)
#pragma unroll
      for (int m = 0; m < 4; ++m)
#pragma unroll
        for (int r = 0; r < 4; ++r) ss[m][r] += __shfl_xor(ss[m][r], mask);
    // one lane per (m,r) publishes its group's row partial (this wave's 64 cols)
#pragma unroll
    for (int m = 0; m < 4; ++m)
#pragma unroll
      for (int r = 0; r < 4; ++r)
        if (lr == (m << 2 | r)) ssred[w & 1][wr + m * 16 + g4 * 4 + r] = ss[m][r];
    __syncthreads();
    uint16_t* outp = (mode == 0) ? Qn : Kn;
    const int NHv = (mode == 0) ? H_ : KVH_;
    const float gmul = (mode == 0) ? g[h] * 0.08838834764831845f : 1.0f;  // fold 1/sqrt(128)
#pragma unroll
    for (int m = 0; m < 4; ++m)
#pragma unroll
      for (int r = 0; r < 4; ++r) {
        int row = wr + m * 16 + g4 * 4 + r;
        float tot = ssred[0][row] + ssred[1][row];
        float scl = gmul / fmaxf(sqrtf(tot), 1e-12f);
        size_t base = ((size_t)(b * NHv + h) * T_ + (t0 + row)) * 128;
#pragma unroll
        for (int n = 0; n < 4; ++n)
          outp[base + wc + n * 16 + lr] = f2bf(acc[m][n][r] * scl);
      }
  } else {
    // ---- fused transpose epilogue: write Vt (B,KVH,128,T) via LDS bounce ----
    uint16_t* tr = smem;  // stride 132 elems (264B -> 2-dword bank skew per row)
#pragma unroll
    for (int m = 0; m < 4; ++m)
#pragma unroll
      for (int n = 0; n < 4; ++n)
#pragma unroll
        for (int r = 0; r < 4; ++r)
          tr[(wc + n * 16 + lr) * 132 + (wr + m * 16 + r04 + r)] = f2bf(acc[m][n][r]);
    __syncthreads();
    const int qd = tid & 3;
#pragma unroll
    for (int dd = 0; dd < 2; ++dd) {
      int d = (tid >> 2) + dd * 64;
      uint16_t* dst = Vt + ((size_t)(b * KVH_ + h) * 128 + d) * T_ + t0 + qd * 32;
      const uint16_t* srcl = &tr[d * 132 + qd * 32];
#pragma unroll
      for (int j = 0; j < 8; ++j)
        *(ushort4*)(dst + j * 4) = *(const ushort4*)(srcl + j * 4);
    }
  }
}

// ---------------- causal GQA flash attention, paired q-tiles ----------------
__global__ __launch_bounds__(256) void k_attn(const uint16_t* __restrict__ Qn,
                                              const uint16_t* __restrict__ Kn,
                                              const uint16_t* __restrict__ Vt,
                                              uint16_t* __restrict__ Y) {
  __shared__ uint16_t Ks[64 * 128];
  __shared__ uint16_t Vs[128 * 64];
  __shared__ uint16_t Ps[4 * 16 * 32];
  const int npair = T_ / 128;              // 16
  const int pair_id = blockIdx.x % npair;
  const int bh = blockIdx.x / npair;
  const int h = bh % H_;
  const int b = bh / H_;
  const int kvh = h >> 2;
  const int qtA = pair_id;                 // light tile
  const int qtB = (T_ / 64) - 1 - pair_id; // heavy tile
  const uint16_t* Qh = Qn + ((size_t)(b * H_ + h) * T_) * 128;
  const uint16_t* Kh = Kn + ((size_t)(b * KVH_ + kvh) * T_) * 128;
  const uint16_t* Vh = Vt + ((size_t)(b * KVH_ + kvh) * 128) * T_;
  const int tid = threadIdx.x;
  const int w = tid >> 6, lane = tid & 63;
  const int lr = lane & 15;
  const int lk2 = (lane >> 4) << 4;        // byte offset of k-slice within row
  const int r0 = (lane >> 4) << 2;
  const int qwA = qtA * 64 + w * 16;
  const int qwB = qtB * 64 + w * 16;
  char* Psw = (char*)Ps + w * 1024;

  bf16x8 qfA[4], qfB[4];
#pragma unroll
  for (int dblk = 0; dblk < 4; ++dblk) {
    qfA[dblk] = *(const bf16x8*)&Qh[(size_t)(qwA + lr) * 128 + dblk * 32 + (lk2 >> 1)];
    qfB[dblk] = *(const bf16x8*)&Qh[(size_t)(qwB + lr) * 128 + dblk * 32 + (lk2 >> 1)];
  }
  union { uint16_t u[8]; bf16x8 v; } ou;
#pragma unroll
  for (int j = 0; j < 8; ++j) ou.u[j] = 0x3F80;  // bf16(1.0)
  const bf16x8 ones = ou.v;
  f32x4 oA[8] = {}, oB[8] = {};
  f32x4 sumA = {}, sumB = {};

  auto tilecompute = [&](const bf16x8* qf, f32x4* o, f32x4* sum, int qw, int kv0) {
#pragma unroll
    for (int prr = 0; prr < 2; ++prr) {
#pragma unroll
      for (int kbi = 0; kbi < 2; ++kbi) {
        int kb = prr * 2 + kbi;
        f32x4 s = {};
#pragma unroll
        for (int dblk = 0; dblk < 4; ++dblk) {
          bf16x8 kf = *(const bf16x8*)((const char*)Ks +
              ((kb * 16 + lr) << 8) + ((dblk * 64 + lk2) ^ ((lr & 7) << 4)));
          s = __builtin_amdgcn_mfma_f32_16x16x32_bf16(qf[dblk], kf, s, 0, 0, 0);
        }
        int kval = kv0 + kb * 16 + lr;   // C/D col = lane&15 = k index
#pragma unroll
        for (int r = 0; r < 4; ++r) {
          float pv = (kval <= qw + r0 + r) ? __expf(s[r]) : 0.0f;
          *(uint16_t*)(Psw + (r0 + r) * 64 + (((kbi * 16 + lr) * 2) ^ (r << 4))) = f2bf(pv);
        }
      }
      asm volatile("s_waitcnt lgkmcnt(0)" ::: "memory");
      bf16x8 pa = *(const bf16x8*)(Psw + lr * 64 + (lk2 ^ ((lr & 3) << 4)));
#pragma unroll
      for (int dblk = 0; dblk < 8; ++dblk) {
        bf16x8 vf = *(const bf16x8*)((const char*)Vs +
            ((dblk * 16 + lr) << 7) + ((prr * 64 + lk2) ^ ((lr & 7) << 4)));
        o[dblk] = __builtin_amdgcn_mfma_f32_16x16x32_bf16(pa, vf, o[dblk], 0, 0, 0);
      }
      *sum = __builtin_amdgcn_mfma_f32_16x16x32_bf16(pa, ones, *sum, 0, 0, 0);
    }
  };

  for (int tile = 0; tile <= qtB; ++tile) {
    const int kv0 = tile * 64;
#pragma unroll
    for (int i = 0; i < 4; ++i) {
      int off = i * 4096 + tid * 16;
      int krow = off >> 8;
      int kchunk = (off >> 4) & 15;
      int kcol = (kchunk ^ (krow & 7)) << 3;
      async16(Kh + (size_t)(kv0 + krow) * 128 + kcol, (char*)Ks + off);
      int vrow = off >> 7;
      int vchunk = (off >> 4) & 7;
      int vcol = (vchunk ^ (vrow & 7)) << 3;
      async16(Vh + (size_t)vrow * T_ + kv0 + vcol, (char*)Vs + off);
    }
    __syncthreads();
    tilecompute(qfB, oB, &sumB, qwB, kv0);
    if (tile <= qtA) tilecompute(qfA, oA, &sumA, qwA, kv0);
    __syncthreads();
  }

  auto writeout = [&](const f32x4* o, const f32x4& sum, int qw) {
#pragma unroll
    for (int r = 0; r < 4; ++r) {
      float inv = 1.0f / sum[r];
      size_t base = ((size_t)b * T_ + (qw + r0 + r)) * D_ + h * 128 + lr;
#pragma unroll
      for (int dblk = 0; dblk < 8; ++dblk)
        Y[base + dblk * 16] = f2bf(o[dblk][r] * inv);
    }
  };
  writeout(oA, sumA, qwA);
  writeout(oB, sumB, qwB);
}

extern "C" void kernel_launch(void* const* d_in, const int* in_sizes, int n_in,
                              void* d_out, int out_size, void* d_ws, size_t ws_size,
                              hipStream_t stream) {
  (void)in_sizes; (void)n_in; (void)out_size; (void)ws_size;
  const float* q  = (const float*)d_in[0];
  const float* k  = (const float*)d_in[1];
  const float* v  = (const float*)d_in[2];
  const float* Wq = (const float*)d_in[3];
  const float* Wk = (const float*)d_in[4];
  const float* Wv = (const float*)d_in[5];
  const float* Wo = (const float*)d_in[6];
  const float* g  = (const float*)d_in[7];
  float* out = (float*)d_out;
  char* ws = (char*)d_ws;
  const size_t MB = 1ull << 20;
  uint16_t* qb  = (uint16_t*)(ws);             // 16MB; reused as Y after k_proj
  uint16_t* kb  = (uint16_t*)(ws + 16 * MB);   // 16MB; reused as Wob after k_proj
  uint16_t* vb  = (uint16_t*)(ws + 32 * MB);   // 16MB
  uint16_t* Wqb = (uint16_t*)(ws + 48 * MB);   // 8MB
  uint16_t* Wkb = (uint16_t*)(ws + 56 * MB);   // 2MB
  uint16_t* Wvb = (uint16_t*)(ws + 58 * MB);   // 2MB
  uint16_t* Kn  = (uint16_t*)(ws + 60 * MB);   // 4MB
  uint16_t* Vtb = (uint16_t*)(ws + 64 * MB);   // 4MB  (ws high-water: 68MB)
  uint16_t* Qn  = (uint16_t*)d_out;            // 16MB scratch inside 32MB d_out;
                                               // dead before final GEMM overwrites d_out
  uint16_t* Y   = qb;
  uint16_t* Wob = kb;

  // 1) convert all six early inputs in one launch
  k_cvt_all<<<15360, 256, 0, stream>>>(q, k, v, Wq, Wk, Wv, qb, kb, vb, Wqb, Wkb, Wvb);
  // 2) merged Q/K/V projection with fused norm / transpose epilogues
  k_proj<<<768, 256, 0, stream>>>(qb, kb, vb, Wqb, Wkb, Wvb, Qn, Kn, Vtb, g);
  // 3) Wo convert (kb region is dead now)
  k_cvt<<<2048, 256, 0, stream>>>(Wo, Wob, (D_ * D_) / 8);
  // 4) attention (reads Qn from d_out region, writes Y into qb)
  k_attn<<<B_ * H_ * (T_ / 128), 256, 0, stream>>>(Qn, Kn, Vtb, Y);
  // 5) output projection (fp32 out; overwrites d_out including dead Qn)
  k_gemm_bt<<<(B_ * T_ / 128) * (D_ / 128), 256, 0, stream>>>(Y, Wob, out, B_ * T_, D_, D_);
}

// Round 6
// 238.178 us; speedup vs baseline: 1.9235x; 1.0141x over previous
//
#include <hip/hip_runtime.h>
#include <hip/hip_bf16.h>
#include <stdint.h>

#define B_ 2
#define T_ 2048
#define D_ 2048
#define H_ 16
#define KVH_ 4
#define DK_ 128

typedef __bf16 bf16x8 __attribute__((ext_vector_type(8)));
typedef float f32x4 __attribute__((ext_vector_type(4)));
typedef unsigned short u16x8 __attribute__((ext_vector_type(8)));

typedef __attribute__((address_space(1))) void* gas1_t;
typedef __attribute__((address_space(3))) void* gas3_t;

__device__ __forceinline__ uint16_t f2bf(float f) {
  uint32_t u = __builtin_bit_cast(uint32_t, f);
  u += 0x7FFFu + ((u >> 16) & 1u);
  return (uint16_t)(u >> 16);
}

__device__ __forceinline__ void async16(const void* g, void* l) {
  __builtin_amdgcn_global_load_lds((gas1_t)(uintptr_t)g, (gas3_t)l, 16, 0, 0);
}

// ---------------- fp32 -> bf16 convert (single buffer) ----------------
__global__ __launch_bounds__(256) void k_cvt(const float* __restrict__ s,
                                             uint16_t* __restrict__ d, int n8) {
  int i = blockIdx.x * 256 + threadIdx.x;
  if (i >= n8) return;
  const float4* s4 = (const float4*)s;
  float4 a = s4[(size_t)i * 2], b = s4[(size_t)i * 2 + 1];
  union { uint16_t u[8]; uint4 v; } o;
  o.u[0] = f2bf(a.x); o.u[1] = f2bf(a.y); o.u[2] = f2bf(a.z); o.u[3] = f2bf(a.w);
  o.u[4] = f2bf(b.x); o.u[5] = f2bf(b.y); o.u[6] = f2bf(b.z); o.u[7] = f2bf(b.w);
  ((uint4*)d)[i] = o.v;
}

// ---------------- all-inputs fp32 -> bf16 convert, one launch ----------------
__global__ __launch_bounds__(256) void k_cvt_all(const float* __restrict__ q,
                                                 const float* __restrict__ k,
                                                 const float* __restrict__ v,
                                                 const float* __restrict__ wq,
                                                 const float* __restrict__ wk,
                                                 const float* __restrict__ wv,
                                                 uint16_t* __restrict__ qb,
                                                 uint16_t* __restrict__ kb,
                                                 uint16_t* __restrict__ vb,
                                                 uint16_t* __restrict__ wqb,
                                                 uint16_t* __restrict__ wkb,
                                                 uint16_t* __restrict__ wvb) {
  int gb = blockIdx.x;
  const float* s; uint16_t* d; int base;
  if (gb < 4096)        { s = q;  d = qb;  base = 0; }
  else if (gb < 8192)   { s = k;  d = kb;  base = 4096; }
  else if (gb < 12288)  { s = v;  d = vb;  base = 8192; }
  else if (gb < 14336)  { s = wq; d = wqb; base = 12288; }
  else if (gb < 14848)  { s = wk; d = wkb; base = 14336; }
  else                  { s = wv; d = wvb; base = 14848; }
  int i = (gb - base) * 256 + threadIdx.x;
  const float4* s4 = (const float4*)s;
  float4 a = s4[(size_t)i * 2], b = s4[(size_t)i * 2 + 1];
  union { uint16_t u[8]; uint4 v; } o;
  o.u[0] = f2bf(a.x); o.u[1] = f2bf(a.y); o.u[2] = f2bf(a.z); o.u[3] = f2bf(a.w);
  o.u[4] = f2bf(b.x); o.u[5] = f2bf(b.y); o.u[6] = f2bf(b.z); o.u[7] = f2bf(b.w);
  ((uint4*)d)[i] = o.v;
}

// ============ 256x256-tile phase-pipelined bf16 GEMM (K=2048, B^T) ============
// 8 waves (2M x 4N), per-wave 128x64 out (acc[8][4]). BK=32, ring-4 LDS K-tiles,
// staged 3 ahead via global_load_lds; counted vmcnt(8) at K-tile boundaries only.
// LDS swizzle: 16B slot j at row r holds logical k-slice j^(r&3) (both sides).
// WHICH=0: merged QKV proj (bid<128 Q->l2norm*g; <160 K->l2norm; else V->transpose)
// WHICH=1: plain A*W^T -> fp32 C.
template <int WHICH>
__global__ __launch_bounds__(512, 2) void k_mm256(
    const uint16_t* __restrict__ qb, const uint16_t* __restrict__ kb,
    const uint16_t* __restrict__ vb,
    const uint16_t* __restrict__ Wqb, const uint16_t* __restrict__ Wkb,
    const uint16_t* __restrict__ Wvb,
    uint16_t* __restrict__ Qn, uint16_t* __restrict__ Kn,
    uint16_t* __restrict__ Vt, const float* __restrict__ g,
    float* __restrict__ Cout) {
  __shared__ char lds[131072];          // A-ring [4][16KB] @0, B-ring [4][16KB] @64KB
  __shared__ float ssred[4][256];
  char* Alds = lds;
  char* Blds = lds + 65536;

  const int tid = threadIdx.x;
  const int wv = tid >> 6, lane = tid & 63;
  const int wr = wv >> 2, wc = wv & 3;
  const int lr = lane & 15, g4 = lane >> 4;

  const uint16_t *A, *W;
  int m0, n0, mode;
  if (WHICH == 1) {
    mode = 3; A = qb; W = Wqb;     // repurposed: qb=Y, Wqb=Wob
    m0 = (blockIdx.x >> 3) << 8; n0 = (blockIdx.x & 7) << 8;
  } else {
    int bid = blockIdx.x;
    if (bid < 128)      { mode = 0; A = qb; W = Wqb; m0 = (bid >> 3) << 8; n0 = (bid & 7) << 8; }
    else if (bid < 160) { int lb = bid - 128; mode = 1; A = kb; W = Wkb; m0 = (lb >> 1) << 8; n0 = (lb & 1) << 8; }
    else                { int lb = bid - 160; mode = 2; A = vb; W = Wvb; m0 = (lb >> 1) << 8; n0 = (lb & 1) << 8; }
  }

  // staging geometry: per tile, 2 A-loads + 2 B-loads per thread (16B each)
  const int off0 = tid * 16;                 // LDS byte offset, load 0
  const int off1 = 8192 + tid * 16;          // load 1 (+128 rows)
  const int row0 = off0 >> 6;                // 0..127
  const int j0 = ((off0 >> 4) & 3) ^ (row0 & 3);
  const uint16_t* aS0 = A + (size_t)(m0 + row0) * 2048 + j0 * 8;
  const uint16_t* aS1 = A + (size_t)(m0 + row0 + 128) * 2048 + j0 * 8;
  const uint16_t* bS0 = W + (size_t)(n0 + row0) * 2048 + j0 * 8;
  const uint16_t* bS1 = W + (size_t)(n0 + row0 + 128) * 2048 + j0 * 8;

  // ds-read bases (swizzled): row*64 + (j ^ (row&3))*16, j = lane>>4, row&3 = lane&3
  const int jsw = ((lane >> 4) ^ (lane & 3)) << 4;
  const int abase = (wr * 128 + lr) * 64 + jsw;
  const int bbase = (wc * 64 + lr) * 64 + jsw;

  f32x4 acc[8][4] = {};

  auto stageA = [&](int ks) {
    int sb = (ks & 3) << 14;
    async16(aS0 + ks * 32, Alds + sb + off0);
    async16(aS1 + ks * 32, Alds + sb + off1);
  };
  auto stageB = [&](int ks) {
    int sb = (ks & 3) << 14;
    async16(bS0 + ks * 32, Blds + sb + off0);
    async16(bS1 + ks * 32, Blds + sb + off1);
  };

  // prologue: stage tiles 0,1,2 (12 loads); wait until tile0 (oldest 4) landed
  stageA(0); stageB(0); stageA(1); stageB(1); stageA(2); stageB(2);
  asm volatile("s_waitcnt vmcnt(8)" ::: "memory");
  __builtin_amdgcn_s_barrier();

  for (int kt = 0; kt < 64; ++kt) {
    const char* As_ = Alds + ((kt & 3) << 14);
    const char* Bs_ = Blds + ((kt & 3) << 14);
    bf16x8 a[4], b[4], a2[4];
    // ---- phase 0: m=0..3 quadrant ----
#pragma unroll
    for (int m = 0; m < 4; ++m) a[m] = *(const bf16x8*)(As_ + abase + m * 1024);
#pragma unroll
    for (int n = 0; n < 4; ++n) b[n] = *(const bf16x8*)(Bs_ + bbase + n * 1024);
    if (kt + 3 < 64) stageA(kt + 3);
    __builtin_amdgcn_s_barrier();
    __builtin_amdgcn_s_setprio(1);
#pragma unroll
    for (int m = 0; m < 4; ++m)
#pragma unroll
      for (int n = 0; n < 4; ++n)
        acc[m][n] = __builtin_amdgcn_mfma_f32_16x16x32_bf16(a[m], b[n], acc[m][n], 0, 0, 0);
    __builtin_amdgcn_s_setprio(0);
    __builtin_amdgcn_s_barrier();
    // ---- phase 1: m=4..7 quadrant ----
#pragma unroll
    for (int m = 0; m < 4; ++m) a2[m] = *(const bf16x8*)(As_ + abase + (m + 4) * 1024);
    if (kt + 3 < 64) stageB(kt + 3);
    __builtin_amdgcn_s_barrier();
    __builtin_amdgcn_s_setprio(1);
#pragma unroll
    for (int m = 0; m < 4; ++m)
#pragma unroll
      for (int n = 0; n < 4; ++n)
        acc[m + 4][n] = __builtin_amdgcn_mfma_f32_16x16x32_bf16(a2[m], b[n], acc[m + 4][n], 0, 0, 0);
    __builtin_amdgcn_s_setprio(0);
    // counted wait: tiles kt+2,kt+3 may stay in flight (8 loads); kt+1 landed
    if (kt < 61)       asm volatile("s_waitcnt vmcnt(8)" ::: "memory");
    else if (kt == 61) asm volatile("s_waitcnt vmcnt(4)" ::: "memory");
    else if (kt == 62) asm volatile("s_waitcnt vmcnt(0)" ::: "memory");
    __builtin_amdgcn_s_barrier();
  }

  const int bb = m0 >> 11;
  const int t0 = m0 & (T_ - 1);

  if (WHICH == 1 || mode == 3) {
    // ---- fp32 C write ----
#pragma unroll
    for (int m = 0; m < 8; ++m)
#pragma unroll
      for (int n = 0; n < 4; ++n)
#pragma unroll
        for (int r = 0; r < 4; ++r)
          Cout[(size_t)(m0 + wr * 128 + m * 16 + g4 * 4 + r) * 2048 +
               n0 + wc * 64 + n * 16 + lr] = acc[m][n][r];
  } else if (mode <= 1) {
    // ---- fused l2norm epilogue (tile = 2 heads of 128 cols) ----
    float ss[8][4];
#pragma unroll
    for (int m = 0; m < 8; ++m)
#pragma unroll
      for (int r = 0; r < 4; ++r) {
        float s = 0.f;
#pragma unroll
        for (int n = 0; n < 4; ++n) s += acc[m][n][r] * acc[m][n][r];
        ss[m][r] = s;
      }
#pragma unroll
    for (int mask = 1; mask < 16; mask <<= 1)
#pragma unroll
      for (int m = 0; m < 8; ++m)
#pragma unroll
        for (int r = 0; r < 4; ++r) ss[m][r] += __shfl_xor(ss[m][r], mask);
#pragma unroll
    for (int m = 0; m < 8; ++m)
#pragma unroll
      for (int r = 0; r < 4; ++r)
        if (lr == ((m << 2 | r) & 15))
          ssred[wc][wr * 128 + m * 16 + g4 * 4 + r] = ss[m][r];
    __syncthreads();
    uint16_t* outp = (mode == 0) ? Qn : Kn;
    const int NHv = (mode == 0) ? H_ : KVH_;
    const int h = (n0 >> 7) + (wc >> 1);
    const float gmul = (mode == 0) ? g[h] * 0.08838834764831845f : 1.0f;
    const int wp = wc & 2;
#pragma unroll
    for (int m = 0; m < 8; ++m)
#pragma unroll
      for (int r = 0; r < 4; ++r) {
        int row = wr * 128 + m * 16 + g4 * 4 + r;
        float tot = ssred[wp][row] + ssred[wp | 1][row];
        float scl = gmul / fmaxf(sqrtf(tot), 1e-12f);
        size_t base = ((size_t)(bb * NHv + h) * T_ + (t0 + row)) * 128 + (wc & 1) * 64 + lr;
#pragma unroll
        for (int n = 0; n < 4; ++n)
          outp[base + n * 16] = f2bf(acc[m][n][r] * scl);
      }
  } else {
    // ---- fused V-transpose epilogue, two passes of 128 cols via LDS bounce ----
    uint16_t (*tr)[264] = (uint16_t(*)[264])lds;
#pragma unroll
    for (int p = 0; p < 2; ++p) {
      __syncthreads();
      if ((wc >> 1) == p) {
#pragma unroll
        for (int m = 0; m < 8; ++m)
#pragma unroll
          for (int n = 0; n < 4; ++n)
#pragma unroll
            for (int r = 0; r < 4; ++r)
              tr[(wc & 1) * 64 + n * 16 + lr][wr * 128 + m * 16 + g4 * 4 + r] =
                  f2bf(acc[m][n][r]);
      }
      __syncthreads();
      int c2 = tid >> 2, rq = tid & 3;                // col 0..127, row-quarter
      int h = (n0 >> 7) + p;
      uint16_t* dst = Vt + ((size_t)(bb * KVH_ + h) * 128 + c2) * T_ + t0 + rq * 64;
      const uint16_t* src = &tr[c2][rq * 64];
#pragma unroll
      for (int jj = 0; jj < 8; ++jj)
        *(u16x8*)(dst + jj * 8) = *(const u16x8*)(src + jj * 8);
    }
  }
}

// ---------------- causal GQA flash attention, paired q-tiles ----------------
__global__ __launch_bounds__(256) void k_attn(const uint16_t* __restrict__ Qn,
                                              const uint16_t* __restrict__ Kn,
                                              const uint16_t* __restrict__ Vt,
                                              uint16_t* __restrict__ Y) {
  __shared__ uint16_t Ks[64 * 128];
  __shared__ uint16_t Vs[128 * 64];
  __shared__ uint16_t Ps[4 * 16 * 32];
  const int npair = T_ / 128;              // 16
  const int pair_id = blockIdx.x % npair;
  const int bh = blockIdx.x / npair;
  const int h = bh % H_;
  const int b = bh / H_;
  const int kvh = h >> 2;
  const int qtA = pair_id;                 // light tile
  const int qtB = (T_ / 64) - 1 - pair_id; // heavy tile
  const uint16_t* Qh = Qn + ((size_t)(b * H_ + h) * T_) * 128;
  const uint16_t* Kh = Kn + ((size_t)(b * KVH_ + kvh) * T_) * 128;
  const uint16_t* Vh = Vt + ((size_t)(b * KVH_ + kvh) * 128) * T_;
  const int tid = threadIdx.x;
  const int w = tid >> 6, lane = tid & 63;
  const int lr = lane & 15;
  const int lk2 = (lane >> 4) << 4;
  const int r0 = (lane >> 4) << 2;
  const int qwA = qtA * 64 + w * 16;
  const int qwB = qtB * 64 + w * 16;
  char* Psw = (char*)Ps + w * 1024;

  bf16x8 qfA[4], qfB[4];
#pragma unroll
  for (int dblk = 0; dblk < 4; ++dblk) {
    qfA[dblk] = *(const bf16x8*)&Qh[(size_t)(qwA + lr) * 128 + dblk * 32 + (lk2 >> 1)];
    qfB[dblk] = *(const bf16x8*)&Qh[(size_t)(qwB + lr) * 128 + dblk * 32 + (lk2 >> 1)];
  }
  union { uint16_t u[8]; bf16x8 v; } ou;
#pragma unroll
  for (int j = 0; j < 8; ++j) ou.u[j] = 0x3F80;
  const bf16x8 ones = ou.v;
  f32x4 oA[8] = {}, oB[8] = {};
  f32x4 sumA = {}, sumB = {};

  auto tilecompute = [&](const bf16x8* qf, f32x4* o, f32x4* sum, int qw, int kv0) {
#pragma unroll
    for (int prr = 0; prr < 2; ++prr) {
#pragma unroll
      for (int kbi = 0; kbi < 2; ++kbi) {
        int kb = prr * 2 + kbi;
        f32x4 s = {};
#pragma unroll
        for (int dblk = 0; dblk < 4; ++dblk) {
          bf16x8 kf = *(const bf16x8*)((const char*)Ks +
              ((kb * 16 + lr) << 8) + ((dblk * 64 + lk2) ^ ((lr & 7) << 4)));
          s = __builtin_amdgcn_mfma_f32_16x16x32_bf16(qf[dblk], kf, s, 0, 0, 0);
        }
        int kval = kv0 + kb * 16 + lr;
#pragma unroll
        for (int r = 0; r < 4; ++r) {
          float pv = (kval <= qw + r0 + r) ? __expf(s[r]) : 0.0f;
          *(uint16_t*)(Psw + (r0 + r) * 64 + (((kbi * 16 + lr) * 2) ^ (r << 4))) = f2bf(pv);
        }
      }
      asm volatile("s_waitcnt lgkmcnt(0)" ::: "memory");
      bf16x8 pa = *(const bf16x8*)(Psw + lr * 64 + (lk2 ^ ((lr & 3) << 4)));
#pragma unroll
      for (int dblk = 0; dblk < 8; ++dblk) {
        bf16x8 vf = *(const bf16x8*)((const char*)Vs +
            ((dblk * 16 + lr) << 7) + ((prr * 64 + lk2) ^ ((lr & 7) << 4)));
        o[dblk] = __builtin_amdgcn_mfma_f32_16x16x32_bf16(pa, vf, o[dblk], 0, 0, 0);
      }
      *sum = __builtin_amdgcn_mfma_f32_16x16x32_bf16(pa, ones, *sum, 0, 0, 0);
    }
  };

  for (int tile = 0; tile <= qtB; ++tile) {
    const int kv0 = tile * 64;
#pragma unroll
    for (int i = 0; i < 4; ++i) {
      int off = i * 4096 + tid * 16;
      int krow = off >> 8;
      int kchunk = (off >> 4) & 15;
      int kcol = (kchunk ^ (krow & 7)) << 3;
      async16(Kh + (size_t)(kv0 + krow) * 128 + kcol, (char*)Ks + off);
      int vrow = off >> 7;
      int vchunk = (off >> 4) & 7;
      int vcol = (vchunk ^ (vrow & 7)) << 3;
      async16(Vh + (size_t)vrow * T_ + kv0 + vcol, (char*)Vs + off);
    }
    __syncthreads();
    tilecompute(qfB, oB, &sumB, qwB, kv0);
    if (tile <= qtA) tilecompute(qfA, oA, &sumA, qwA, kv0);
    __syncthreads();
  }

  auto writeout = [&](const f32x4* o, const f32x4& sum, int qw) {
#pragma unroll
    for (int r = 0; r < 4; ++r) {
      float inv = 1.0f / sum[r];
      size_t base = ((size_t)b * T_ + (qw + r0 + r)) * D_ + h * 128 + lr;
#pragma unroll
      for (int dblk = 0; dblk < 8; ++dblk)
        Y[base + dblk * 16] = f2bf(o[dblk][r] * inv);
    }
  };
  writeout(oA, sumA, qwA);
  writeout(oB, sumB, qwB);
}

extern "C" void kernel_launch(void* const* d_in, const int* in_sizes, int n_in,
                              void* d_out, int out_size, void* d_ws, size_t ws_size,
                              hipStream_t stream) {
  (void)in_sizes; (void)n_in; (void)out_size; (void)ws_size;
  const float* q  = (const float*)d_in[0];
  const float* k  = (const float*)d_in[1];
  const float* v  = (const float*)d_in[2];
  const float* Wq = (const float*)d_in[3];
  const float* Wk = (const float*)d_in[4];
  const float* Wv = (const float*)d_in[5];
  const float* Wo = (const float*)d_in[6];
  const float* g  = (const float*)d_in[7];
  float* out = (float*)d_out;
  char* ws = (char*)d_ws;
  const size_t MB = 1ull << 20;
  uint16_t* qb  = (uint16_t*)(ws);             // 16MB; reused as Y after k_proj
  uint16_t* kb  = (uint16_t*)(ws + 16 * MB);   // 16MB; reused as Wob after k_proj
  uint16_t* vb  = (uint16_t*)(ws + 32 * MB);   // 16MB
  uint16_t* Wqb = (uint16_t*)(ws + 48 * MB);   // 8MB
  uint16_t* Wkb = (uint16_t*)(ws + 56 * MB);   // 2MB
  uint16_t* Wvb = (uint16_t*)(ws + 58 * MB);   // 2MB
  uint16_t* Kn  = (uint16_t*)(ws + 60 * MB);   // 4MB
  uint16_t* Vtb = (uint16_t*)(ws + 64 * MB);   // 4MB  (ws high-water: 68MB)
  uint16_t* Qn  = (uint16_t*)d_out;            // 16MB scratch in d_out; dead
                                               // before final GEMM overwrites it
  uint16_t* Y   = qb;
  uint16_t* Wob = kb;

  // 1) convert all six early inputs in one launch
  k_cvt_all<<<15360, 256, 0, stream>>>(q, k, v, Wq, Wk, Wv, qb, kb, vb, Wqb, Wkb, Wvb);
  // 2) merged 256^2 pipelined Q/K/V projection with fused norm / transpose
  k_mm256<0><<<192, 512, 0, stream>>>(qb, kb, vb, Wqb, Wkb, Wvb, Qn, Kn, Vtb, g, nullptr);
  // 3) Wo convert (kb region dead now)
  k_cvt<<<2048, 256, 0, stream>>>(Wo, Wob, (D_ * D_) / 8);
  // 4) attention (reads Qn from d_out, writes Y into qb)
  k_attn<<<B_ * H_ * (T_ / 128), 256, 0, stream>>>(Qn, Kn, Vtb, Y);
  // 5) output projection: Y * Wob^T -> fp32 out
  k_mm256<1><<<128, 512, 0, stream>>>(Y, nullptr, nullptr, Wob, nullptr, nullptr,
                                      nullptr, nullptr, nullptr, nullptr, out);
}

// Round 7
// 234.248 us; speedup vs baseline: 1.9558x; 1.0168x over previous
//
#include <hip/hip_runtime.h>
#include <hip/hip_bf16.h>
#include <stdint.h>

#define B_ 2
#define T_ 2048
#define D_ 2048
#define H_ 16
#define KVH_ 4
#define DK_ 128

typedef __bf16 bf16x8 __attribute__((ext_vector_type(8)));
typedef float f32x4 __attribute__((ext_vector_type(4)));
typedef unsigned short u16x8 __attribute__((ext_vector_type(8)));

typedef __attribute__((address_space(1))) void* gas1_t;
typedef __attribute__((address_space(3))) void* gas3_t;

__device__ __forceinline__ uint16_t f2bf(float f) {
  uint32_t u = __builtin_bit_cast(uint32_t, f);
  u += 0x7FFFu + ((u >> 16) & 1u);
  return (uint16_t)(u >> 16);
}

__device__ __forceinline__ void async16(const void* g, void* l) {
  __builtin_amdgcn_global_load_lds((gas1_t)(uintptr_t)g, (gas3_t)l, 16, 0, 0);
}

// ---------------- fp32 -> bf16 convert (single buffer) ----------------
__global__ __launch_bounds__(256) void k_cvt(const float* __restrict__ s,
                                             uint16_t* __restrict__ d, int n8) {
  int i = blockIdx.x * 256 + threadIdx.x;
  if (i >= n8) return;
  const float4* s4 = (const float4*)s;
  float4 a = s4[(size_t)i * 2], b = s4[(size_t)i * 2 + 1];
  union { uint16_t u[8]; uint4 v; } o;
  o.u[0] = f2bf(a.x); o.u[1] = f2bf(a.y); o.u[2] = f2bf(a.z); o.u[3] = f2bf(a.w);
  o.u[4] = f2bf(b.x); o.u[5] = f2bf(b.y); o.u[6] = f2bf(b.z); o.u[7] = f2bf(b.w);
  ((uint4*)d)[i] = o.v;
}

// ---------------- all-inputs fp32 -> bf16 convert, one launch ----------------
__global__ __launch_bounds__(256) void k_cvt_all(const float* __restrict__ q,
                                                 const float* __restrict__ k,
                                                 const float* __restrict__ v,
                                                 const float* __restrict__ wq,
                                                 const float* __restrict__ wk,
                                                 const float* __restrict__ wv,
                                                 uint16_t* __restrict__ qb,
                                                 uint16_t* __restrict__ kb,
                                                 uint16_t* __restrict__ vb,
                                                 uint16_t* __restrict__ wqb,
                                                 uint16_t* __restrict__ wkb,
                                                 uint16_t* __restrict__ wvb) {
  int gb = blockIdx.x;
  const float* s; uint16_t* d; int base;
  if (gb < 4096)        { s = q;  d = qb;  base = 0; }
  else if (gb < 8192)   { s = k;  d = kb;  base = 4096; }
  else if (gb < 12288)  { s = v;  d = vb;  base = 8192; }
  else if (gb < 14336)  { s = wq; d = wqb; base = 12288; }
  else if (gb < 14848)  { s = wk; d = wkb; base = 14336; }
  else                  { s = wv; d = wvb; base = 14848; }
  int i = (gb - base) * 256 + threadIdx.x;
  const float4* s4 = (const float4*)s;
  float4 a = s4[(size_t)i * 2], b = s4[(size_t)i * 2 + 1];
  union { uint16_t u[8]; uint4 v; } o;
  o.u[0] = f2bf(a.x); o.u[1] = f2bf(a.y); o.u[2] = f2bf(a.z); o.u[3] = f2bf(a.w);
  o.u[4] = f2bf(b.x); o.u[5] = f2bf(b.y); o.u[6] = f2bf(b.z); o.u[7] = f2bf(b.w);
  ((uint4*)d)[i] = o.v;
}

// ============ 256x256-tile bf16 GEMM, BK=64 double-buffer (K=2048, B^T) ============
// 8 waves (2M x 4N), per-wave 128x64 out (acc[8][4]).
// LDS: 2 bufs x (A [256][128B] + B [256][128B]) = 128 KB.
// Swizzle (st_16x32 style): byte-col ^= ((row>>2)&1)<<5, same involution applied to
// the global_load_lds SOURCE column and the ds_read address.
// 4 phases per K-tile, 16 MFMA each; tile t+1 staged front-loaded (phases 1-2,
// 8x128B txns per gload instr); single vmcnt(0) per K-tile end; raw barriers.
// WHICH=0: merged QKV proj (bid<128 Q->l2norm*g; <160 K->l2norm; else V->transpose)
// WHICH=1: plain A*W^T -> fp32 C.
template <int WHICH>
__global__ __launch_bounds__(512, 2) void k_mm256(
    const uint16_t* __restrict__ qb, const uint16_t* __restrict__ kb,
    const uint16_t* __restrict__ vb,
    const uint16_t* __restrict__ Wqb, const uint16_t* __restrict__ Wkb,
    const uint16_t* __restrict__ Wvb,
    uint16_t* __restrict__ Qn, uint16_t* __restrict__ Kn,
    uint16_t* __restrict__ Vt, const float* __restrict__ g,
    float* __restrict__ Cout) {
  __shared__ char lds[131072];
  __shared__ float ssred[4][256];

  const int tid = threadIdx.x;
  const int wv = tid >> 6, lane = tid & 63;
  const int wr = wv >> 2, wc = wv & 3;
  const int lr = lane & 15, g4 = lane >> 4;

  const uint16_t *A, *W;
  int m0, n0, mode;
  if (WHICH == 1) {
    mode = 3; A = qb; W = Wqb;     // repurposed: qb=Y, Wqb=Wob
    m0 = (blockIdx.x >> 3) << 8; n0 = (blockIdx.x & 7) << 8;
  } else {
    int bid = blockIdx.x;
    if (bid < 128)      { mode = 0; A = qb; W = Wqb; m0 = (bid >> 3) << 8; n0 = (bid & 7) << 8; }
    else if (bid < 160) { int lb = bid - 128; mode = 1; A = kb; W = Wkb; m0 = (lb >> 1) << 8; n0 = (lb & 1) << 8; }
    else                { int lb = bid - 160; mode = 2; A = vb; W = Wvb; m0 = (lb >> 1) << 8; n0 = (lb & 1) << 8; }
  }

  // ---- staging geometry: per K-tile, A = 256 rows x 128B = 4 gloads/thread ----
  // dest row = i*64 + tid/8 (full 128B rows per wave-instr -> 8x128B txns);
  // source col pre-swizzled with the involution.
  const int srow = tid >> 3;                                    // 0..63
  const int scol = ((tid & 7) ^ (((tid >> 5) & 1) << 1)) * 8;   // swizzled elem col
  const uint16_t* aSrc = A + (size_t)(m0 + srow) * 2048 + scol;
  const uint16_t* bSrc = W + (size_t)(n0 + srow) * 2048 + scol;
  const int ldsOff = tid * 16;

  auto stageA = [&](int ts) {
    char* base = lds + ((ts & 1) << 16);
#pragma unroll
    for (int i = 0; i < 4; ++i)
      async16(aSrc + ((size_t)i * 64) * 2048 + ts * 64, base + i * 8192 + ldsOff);
  };
  auto stageB = [&](int ts) {
    char* base = lds + ((ts & 1) << 16) + 32768;
#pragma unroll
    for (int i = 0; i < 4; ++i)
      async16(bSrc + ((size_t)i * 64) * 2048 + ts * 64, base + i * 8192 + ldsOff);
  };

  // ---- ds-read bases (swizzled) ----
  const int swl = ((lr >> 2) & 1) << 5;          // rows 4-7,12-15 (mod 16): +32B
  const int colb = (g4 << 4) ^ swl;              // 16B chunk within kk-half
  const int aoff = (wr * 128 + lr) * 128 + colb;
  const int boff = (wc * 64 + lr) * 128 + colb;

  f32x4 acc[8][4] = {};

  // prologue: stage tile 0, drain, barrier
  stageA(0); stageB(0);
  asm volatile("s_waitcnt vmcnt(0)" ::: "memory");
  __builtin_amdgcn_s_barrier();

  for (int t = 0; t < 32; ++t) {
    const char* Ab = lds + ((t & 1) << 16);
    const char* Bb = Ab + 32768;
    bf16x8 a[4], b[4];
    // ---- phase 1: kk0, m 0-3 ----
#pragma unroll
    for (int m = 0; m < 4; ++m) a[m] = *(const bf16x8*)(Ab + aoff + m * 2048);
#pragma unroll
    for (int n = 0; n < 4; ++n) b[n] = *(const bf16x8*)(Bb + boff + n * 2048);
    if (t < 31) stageA(t + 1);
    __builtin_amdgcn_s_barrier();
    __builtin_amdgcn_s_setprio(1);
#pragma unroll
    for (int m = 0; m < 4; ++m)
#pragma unroll
      for (int n = 0; n < 4; ++n)
        acc[m][n] = __builtin_amdgcn_mfma_f32_16x16x32_bf16(a[m], b[n], acc[m][n], 0, 0, 0);
    __builtin_amdgcn_s_setprio(0);
    __builtin_amdgcn_s_barrier();
    // ---- phase 2: kk0, m 4-7 ----
#pragma unroll
    for (int m = 0; m < 4; ++m) a[m] = *(const bf16x8*)(Ab + aoff + (m + 4) * 2048);
    if (t < 31) stageB(t + 1);
    __builtin_amdgcn_s_barrier();
    __builtin_amdgcn_s_setprio(1);
#pragma unroll
    for (int m = 0; m < 4; ++m)
#pragma unroll
      for (int n = 0; n < 4; ++n)
        acc[m + 4][n] = __builtin_amdgcn_mfma_f32_16x16x32_bf16(a[m], b[n], acc[m + 4][n], 0, 0, 0);
    __builtin_amdgcn_s_setprio(0);
    __builtin_amdgcn_s_barrier();
    // ---- phase 3: kk1, m 0-3 ----
#pragma unroll
    for (int m = 0; m < 4; ++m) a[m] = *(const bf16x8*)(Ab + aoff + m * 2048 + 64);
#pragma unroll
    for (int n = 0; n < 4; ++n) b[n] = *(const bf16x8*)(Bb + boff + n * 2048 + 64);
    __builtin_amdgcn_s_barrier();
    __builtin_amdgcn_s_setprio(1);
#pragma unroll
    for (int m = 0; m < 4; ++m)
#pragma unroll
      for (int n = 0; n < 4; ++n)
        acc[m][n] = __builtin_amdgcn_mfma_f32_16x16x32_bf16(a[m], b[n], acc[m][n], 0, 0, 0);
    __builtin_amdgcn_s_setprio(0);
    __builtin_amdgcn_s_barrier();
    // ---- phase 4: kk1, m 4-7 ----
#pragma unroll
    for (int m = 0; m < 4; ++m) a[m] = *(const bf16x8*)(Ab + aoff + (m + 4) * 2048 + 64);
    __builtin_amdgcn_s_barrier();
    __builtin_amdgcn_s_setprio(1);
#pragma unroll
    for (int m = 0; m < 4; ++m)
#pragma unroll
      for (int n = 0; n < 4; ++n)
        acc[m + 4][n] = __builtin_amdgcn_mfma_f32_16x16x32_bf16(a[m], b[n], acc[m + 4][n], 0, 0, 0);
    __builtin_amdgcn_s_setprio(0);
    // tile t+1 fully landed before anyone reads it next iteration
    asm volatile("s_waitcnt vmcnt(0)" ::: "memory");
    __builtin_amdgcn_s_barrier();
  }

  const int bb = m0 >> 11;
  const int t0 = m0 & (T_ - 1);

  if (WHICH == 1 || mode == 3) {
    // ---- fp32 C write ----
#pragma unroll
    for (int m = 0; m < 8; ++m)
#pragma unroll
      for (int n = 0; n < 4; ++n)
#pragma unroll
        for (int r = 0; r < 4; ++r)
          Cout[(size_t)(m0 + wr * 128 + m * 16 + g4 * 4 + r) * 2048 +
               n0 + wc * 64 + n * 16 + lr] = acc[m][n][r];
  } else if (mode <= 1) {
    // ---- fused l2norm epilogue (tile = 2 heads of 128 cols) ----
    float ss[8][4];
#pragma unroll
    for (int m = 0; m < 8; ++m)
#pragma unroll
      for (int r = 0; r < 4; ++r) {
        float s = 0.f;
#pragma unroll
        for (int n = 0; n < 4; ++n) s += acc[m][n][r] * acc[m][n][r];
        ss[m][r] = s;
      }
#pragma unroll
    for (int mask = 1; mask < 16; mask <<= 1)
#pragma unroll
      for (int m = 0; m < 8; ++m)
#pragma unroll
        for (int r = 0; r < 4; ++r) ss[m][r] += __shfl_xor(ss[m][r], mask);
#pragma unroll
    for (int m = 0; m < 8; ++m)
#pragma unroll
      for (int r = 0; r < 4; ++r)
        if (lr == ((m << 2 | r) & 15))
          ssred[wc][wr * 128 + m * 16 + g4 * 4 + r] = ss[m][r];
    __syncthreads();
    uint16_t* outp = (mode == 0) ? Qn : Kn;
    const int NHv = (mode == 0) ? H_ : KVH_;
    const int h = (n0 >> 7) + (wc >> 1);
    const float gmul = (mode == 0) ? g[h] * 0.08838834764831845f : 1.0f;
    const int wp = wc & 2;
#pragma unroll
    for (int m = 0; m < 8; ++m)
#pragma unroll
      for (int r = 0; r < 4; ++r) {
        int row = wr * 128 + m * 16 + g4 * 4 + r;
        float tot = ssred[wp][row] + ssred[wp | 1][row];
        float scl = gmul / fmaxf(sqrtf(tot), 1e-12f);
        size_t base = ((size_t)(bb * NHv + h) * T_ + (t0 + row)) * 128 + (wc & 1) * 64 + lr;
#pragma unroll
        for (int n = 0; n < 4; ++n)
          outp[base + n * 16] = f2bf(acc[m][n][r] * scl);
      }
  } else {
    // ---- fused V-transpose epilogue, two passes of 128 cols via LDS bounce ----
    uint16_t (*tr)[264] = (uint16_t(*)[264])lds;
#pragma unroll
    for (int p = 0; p < 2; ++p) {
      __syncthreads();
      if ((wc >> 1) == p) {
#pragma unroll
        for (int m = 0; m < 8; ++m)
#pragma unroll
          for (int n = 0; n < 4; ++n)
#pragma unroll
            for (int r = 0; r < 4; ++r)
              tr[(wc & 1) * 64 + n * 16 + lr][wr * 128 + m * 16 + g4 * 4 + r] =
                  f2bf(acc[m][n][r]);
      }
      __syncthreads();
      int c2 = tid >> 2, rq = tid & 3;                // col 0..127, row-quarter
      int h = (n0 >> 7) + p;
      uint16_t* dst = Vt + ((size_t)(bb * KVH_ + h) * 128 + c2) * T_ + t0 + rq * 64;
      const uint16_t* src = &tr[c2][rq * 64];
#pragma unroll
      for (int jj = 0; jj < 8; ++jj)
        *(u16x8*)(dst + jj * 8) = *(const u16x8*)(src + jj * 8);
    }
  }
}

// ---------------- causal GQA flash attention, paired q-tiles ----------------
__global__ __launch_bounds__(256) void k_attn(const uint16_t* __restrict__ Qn,
                                              const uint16_t* __restrict__ Kn,
                                              const uint16_t* __restrict__ Vt,
                                              uint16_t* __restrict__ Y) {
  __shared__ uint16_t Ks[64 * 128];
  __shared__ uint16_t Vs[128 * 64];
  __shared__ uint16_t Ps[4 * 16 * 32];
  const int npair = T_ / 128;              // 16
  const int pair_id = blockIdx.x % npair;
  const int bh = blockIdx.x / npair;
  const int h = bh % H_;
  const int b = bh / H_;
  const int kvh = h >> 2;
  const int qtA = pair_id;                 // light tile
  const int qtB = (T_ / 64) - 1 - pair_id; // heavy tile
  const uint16_t* Qh = Qn + ((size_t)(b * H_ + h) * T_) * 128;
  const uint16_t* Kh = Kn + ((size_t)(b * KVH_ + kvh) * T_) * 128;
  const uint16_t* Vh = Vt + ((size_t)(b * KVH_ + kvh) * 128) * T_;
  const int tid = threadIdx.x;
  const int w = tid >> 6, lane = tid & 63;
  const int lr = lane & 15;
  const int lk2 = (lane >> 4) << 4;
  const int r0 = (lane >> 4) << 2;
  const int qwA = qtA * 64 + w * 16;
  const int qwB = qtB * 64 + w * 16;
  char* Psw = (char*)Ps + w * 1024;

  bf16x8 qfA[4], qfB[4];
#pragma unroll
  for (int dblk = 0; dblk < 4; ++dblk) {
    qfA[dblk] = *(const bf16x8*)&Qh[(size_t)(qwA + lr) * 128 + dblk * 32 + (lk2 >> 1)];
    qfB[dblk] = *(const bf16x8*)&Qh[(size_t)(qwB + lr) * 128 + dblk * 32 + (lk2 >> 1)];
  }
  union { uint16_t u[8]; bf16x8 v; } ou;
#pragma unroll
  for (int j = 0; j < 8; ++j) ou.u[j] = 0x3F80;
  const bf16x8 ones = ou.v;
  f32x4 oA[8] = {}, oB[8] = {};
  f32x4 sumA = {}, sumB = {};

  auto tilecompute = [&](const bf16x8* qf, f32x4* o, f32x4* sum, int qw, int kv0) {
#pragma unroll
    for (int prr = 0; prr < 2; ++prr) {
#pragma unroll
      for (int kbi = 0; kbi < 2; ++kbi) {
        int kb = prr * 2 + kbi;
        f32x4 s = {};
#pragma unroll
        for (int dblk = 0; dblk < 4; ++dblk) {
          bf16x8 kf = *(const bf16x8*)((const char*)Ks +
              ((kb * 16 + lr) << 8) + ((dblk * 64 + lk2) ^ ((lr & 7) << 4)));
          s = __builtin_amdgcn_mfma_f32_16x16x32_bf16(qf[dblk], kf, s, 0, 0, 0);
        }
        int kval = kv0 + kb * 16 + lr;
#pragma unroll
        for (int r = 0; r < 4; ++r) {
          float pv = (kval <= qw + r0 + r) ? __expf(s[r]) : 0.0f;
          *(uint16_t*)(Psw + (r0 + r) * 64 + (((kbi * 16 + lr) * 2) ^ (r << 4))) = f2bf(pv);
        }
      }
      asm volatile("s_waitcnt lgkmcnt(0)" ::: "memory");
      bf16x8 pa = *(const bf16x8*)(Psw + lr * 64 + (lk2 ^ ((lr & 3) << 4)));
#pragma unroll
      for (int dblk = 0; dblk < 8; ++dblk) {
        bf16x8 vf = *(const bf16x8*)((const char*)Vs +
            ((dblk * 16 + lr) << 7) + ((prr * 64 + lk2) ^ ((lr & 7) << 4)));
        o[dblk] = __builtin_amdgcn_mfma_f32_16x16x32_bf16(pa, vf, o[dblk], 0, 0, 0);
      }
      *sum = __builtin_amdgcn_mfma_f32_16x16x32_bf16(pa, ones, *sum, 0, 0, 0);
    }
  };

  for (int tile = 0; tile <= qtB; ++tile) {
    const int kv0 = tile * 64;
#pragma unroll
    for (int i = 0; i < 4; ++i) {
      int off = i * 4096 + tid * 16;
      int krow = off >> 8;
      int kchunk = (off >> 4) & 15;
      int kcol = (kchunk ^ (krow & 7)) << 3;
      async16(Kh + (size_t)(kv0 + krow) * 128 + kcol, (char*)Ks + off);
      int vrow = off >> 7;
      int vchunk = (off >> 4) & 7;
      int vcol = (vchunk ^ (vrow & 7)) << 3;
      async16(Vh + (size_t)vrow * T_ + kv0 + vcol, (char*)Vs + off);
    }
    __syncthreads();
    tilecompute(qfB, oB, &sumB, qwB, kv0);
    if (tile <= qtA) tilecompute(qfA, oA, &sumA, qwA, kv0);
    __syncthreads();
  }

  auto writeout = [&](const f32x4* o, const f32x4& sum, int qw) {
#pragma unroll
    for (int r = 0; r < 4; ++r) {
      float inv = 1.0f / sum[r];
      size_t base = ((size_t)b * T_ + (qw + r0 + r)) * D_ + h * 128 + lr;
#pragma unroll
      for (int dblk = 0; dblk < 8; ++dblk)
        Y[base + dblk * 16] = f2bf(o[dblk][r] * inv);
    }
  };
  writeout(oA, sumA, qwA);
  writeout(oB, sumB, qwB);
}

extern "C" void kernel_launch(void* const* d_in, const int* in_sizes, int n_in,
                              void* d_out, int out_size, void* d_ws, size_t ws_size,
                              hipStream_t stream) {
  (void)in_sizes; (void)n_in; (void)out_size; (void)ws_size;
  const float* q  = (const float*)d_in[0];
  const float* k  = (const float*)d_in[1];
  const float* v  = (const float*)d_in[2];
  const float* Wq = (const float*)d_in[3];
  const float* Wk = (const float*)d_in[4];
  const float* Wv = (const float*)d_in[5];
  const float* Wo = (const float*)d_in[6];
  const float* g  = (const float*)d_in[7];
  float* out = (float*)d_out;
  char* ws = (char*)d_ws;
  const size_t MB = 1ull << 20;
  uint16_t* qb  = (uint16_t*)(ws);             // 16MB; reused as Y after k_mm256<0>
  uint16_t* kb  = (uint16_t*)(ws + 16 * MB);   // 16MB; reused as Wob after k_mm256<0>
  uint16_t* vb  = (uint16_t*)(ws + 32 * MB);   // 16MB
  uint16_t* Wqb = (uint16_t*)(ws + 48 * MB);   // 8MB
  uint16_t* Wkb = (uint16_t*)(ws + 56 * MB);   // 2MB
  uint16_t* Wvb = (uint16_t*)(ws + 58 * MB);   // 2MB
  uint16_t* Kn  = (uint16_t*)(ws + 60 * MB);   // 4MB
  uint16_t* Vtb = (uint16_t*)(ws + 64 * MB);   // 4MB  (ws high-water: 68MB)
  uint16_t* Qn  = (uint16_t*)d_out;            // 16MB scratch in d_out; dead
                                               // before final GEMM overwrites it
  uint16_t* Y   = qb;
  uint16_t* Wob = kb;

  // 1) convert all six early inputs in one launch
  k_cvt_all<<<15360, 256, 0, stream>>>(q, k, v, Wq, Wk, Wv, qb, kb, vb, Wqb, Wkb, Wvb);
  // 2) merged 256^2 BK=64 pipelined Q/K/V projection with fused norm / transpose
  k_mm256<0><<<192, 512, 0, stream>>>(qb, kb, vb, Wqb, Wkb, Wvb, Qn, Kn, Vtb, g, nullptr);
  // 3) Wo convert (kb region dead now)
  k_cvt<<<2048, 256, 0, stream>>>(Wo, Wob, (D_ * D_) / 8);
  // 4) attention (reads Qn from d_out, writes Y into qb)
  k_attn<<<B_ * H_ * (T_ / 128), 256, 0, stream>>>(Qn, Kn, Vtb, Y);
  // 5) output projection: Y * Wob^T -> fp32 out
  k_mm256<1><<<128, 512, 0, stream>>>(Y, nullptr, nullptr, Wob, nullptr, nullptr,
                                      nullptr, nullptr, nullptr, nullptr, out);
}

// Round 8
// 230.806 us; speedup vs baseline: 1.9850x; 1.0149x over previous
//
#include <hip/hip_runtime.h>
#include <hip/hip_bf16.h>
#include <stdint.h>

#define B_ 2
#define T_ 2048
#define D_ 2048
#define H_ 16
#define KVH_ 4
#define DK_ 128

typedef __bf16 bf16x8 __attribute__((ext_vector_type(8)));
typedef float f32x4 __attribute__((ext_vector_type(4)));
typedef unsigned short u16x8 __attribute__((ext_vector_type(8)));

typedef __attribute__((address_space(1))) void* gas1_t;
typedef __attribute__((address_space(3))) void* gas3_t;

__device__ __forceinline__ uint16_t f2bf(float f) {
  uint32_t u = __builtin_bit_cast(uint32_t, f);
  u += 0x7FFFu + ((u >> 16) & 1u);
  return (uint16_t)(u >> 16);
}

__device__ __forceinline__ void async16(const void* g, void* l) {
  __builtin_amdgcn_global_load_lds((gas1_t)(uintptr_t)g, (gas3_t)l, 16, 0, 0);
}

// ---------------- all-inputs fp32 -> bf16 convert, one launch ----------------
// segments (blocks of 256 thr x 8 elem): q 4096, k 4096, v 4096, Wq 2048,
// Wk 512, Wv 512, Wo 2048  -> 17408 blocks
__global__ __launch_bounds__(256) void k_cvt_all(const float* __restrict__ q,
                                                 const float* __restrict__ k,
                                                 const float* __restrict__ v,
                                                 const float* __restrict__ wq,
                                                 const float* __restrict__ wk,
                                                 const float* __restrict__ wv,
                                                 const float* __restrict__ wo,
                                                 uint16_t* __restrict__ qb,
                                                 uint16_t* __restrict__ kb,
                                                 uint16_t* __restrict__ vb,
                                                 uint16_t* __restrict__ wqb,
                                                 uint16_t* __restrict__ wkb,
                                                 uint16_t* __restrict__ wvb,
                                                 uint16_t* __restrict__ wob) {
  int gb = blockIdx.x;
  const float* s; uint16_t* d; int base;
  if (gb < 4096)        { s = q;  d = qb;  base = 0; }
  else if (gb < 8192)   { s = k;  d = kb;  base = 4096; }
  else if (gb < 12288)  { s = v;  d = vb;  base = 8192; }
  else if (gb < 14336)  { s = wq; d = wqb; base = 12288; }
  else if (gb < 14848)  { s = wk; d = wkb; base = 14336; }
  else if (gb < 15360)  { s = wv; d = wvb; base = 14848; }
  else                  { s = wo; d = wob; base = 15360; }
  int i = (gb - base) * 256 + threadIdx.x;
  const float4* s4 = (const float4*)s;
  float4 a = s4[(size_t)i * 2], b = s4[(size_t)i * 2 + 1];
  union { uint16_t u[8]; uint4 v; } o;
  o.u[0] = f2bf(a.x); o.u[1] = f2bf(a.y); o.u[2] = f2bf(a.z); o.u[3] = f2bf(a.w);
  o.u[4] = f2bf(b.x); o.u[5] = f2bf(b.y); o.u[6] = f2bf(b.z); o.u[7] = f2bf(b.w);
  ((uint4*)d)[i] = o.v;
}

// Bank swizzle for [row][128B] LDS tiles read as per-kk-half ds_read_b128:
// stored byte-col = logical byte-col ^ ((row&1)<<6) ^ (((row>>1)&1)<<5).
// Spreads a wave's 64 lanes across all 32 banks at uniform 2-way (free, m136).
// Applied BOTH on the global_load_lds source column and the ds_read address.

// ---------------- bf16 GEMM: C(MxN) = A(MxK) * B(NxK)^T, fp32 out ----------------
__global__ __launch_bounds__(256) void k_gemm_bt(const uint16_t* __restrict__ A,
                                                 const uint16_t* __restrict__ Bm,
                                                 float* __restrict__ C,
                                                 int M, int N, int K) {
  __shared__ uint16_t As[128 * 64];
  __shared__ uint16_t Bs[128 * 64];
  const int tid = threadIdx.x;
  const int nt = N >> 7;
  const int m0 = (blockIdx.x / nt) << 7;
  const int n0 = (blockIdx.x % nt) << 7;
  const int w = tid >> 6, lane = tid & 63;
  const int wr = (w >> 1) << 6, wc = (w & 1) << 6;
  const int lr = lane & 15;
  const int g16 = ((lane >> 4) << 4);                       // g4*16 bytes
  const int csw = ((lane & 1) << 6) | (((lane >> 1) & 1) << 5);
  f32x4 acc[4][4] = {};
  const int soff = tid * 16;
  // staging: row = i*32 + tid>>3; source col pre-swizzled by row bits 0-1
  const int scol = ((tid & 7) ^ (((tid >> 3) & 1) << 2) ^ (((tid >> 4) & 1) << 1)) << 3;
  const int srow = tid >> 3;
  for (int kt = 0; kt < K; kt += 64) {
#pragma unroll
    for (int i = 0; i < 4; ++i) {
      int off = i * 4096 + soff;
      int row = i * 32 + srow;
      async16(A + (size_t)(m0 + row) * K + kt + scol, (char*)As + off);
      async16(Bm + (size_t)(n0 + row) * K + kt + scol, (char*)Bs + off);
    }
    __syncthreads();
#pragma unroll
    for (int kk2 = 0; kk2 < 128; kk2 += 64) {               // kk byte offset
      bf16x8 af[4], bfr[4];
      const int cb = (kk2 + g16) ^ csw;
#pragma unroll
      for (int m = 0; m < 4; ++m)
        af[m] = *(const bf16x8*)((const char*)As + (wr + m * 16 + lr) * 128 + cb);
#pragma unroll
      for (int n = 0; n < 4; ++n)
        bfr[n] = *(const bf16x8*)((const char*)Bs + (wc + n * 16 + lr) * 128 + cb);
#pragma unroll
      for (int m = 0; m < 4; ++m)
#pragma unroll
        for (int n = 0; n < 4; ++n)
          acc[m][n] = __builtin_amdgcn_mfma_f32_16x16x32_bf16(af[m], bfr[n], acc[m][n], 0, 0, 0);
    }
    __syncthreads();
  }
  const int r0 = (lane >> 4) << 2;
  const int c = lane & 15;
#pragma unroll
  for (int m = 0; m < 4; ++m)
#pragma unroll
    for (int n = 0; n < 4; ++n)
#pragma unroll
      for (int r = 0; r < 4; ++r)
        C[(size_t)(m0 + wr + m * 16 + r0 + r) * N + n0 + wc + n * 16 + c] = acc[m][n][r];
}

// ---------------- merged QKV projection with fused epilogues ----------------
// Blocks [0,128): V proj (nt=4) -> transpose -> Vt (B,KVH,128,T) bf16   (heavy, first)
// Blocks [128,256): K proj (nt=4) -> l2norm -> Kn (B,KVH,T,128) bf16
// Blocks [256,768): Q proj (nt=16) -> l2norm*g/sqrt(dk) -> Qn (B,H,T,128) bf16
__global__ __launch_bounds__(256) void k_proj(const uint16_t* __restrict__ qb,
                                              const uint16_t* __restrict__ kb,
                                              const uint16_t* __restrict__ vb,
                                              const uint16_t* __restrict__ Wqb,
                                              const uint16_t* __restrict__ Wkb,
                                              const uint16_t* __restrict__ Wvb,
                                              uint16_t* __restrict__ Qn,
                                              uint16_t* __restrict__ Kn,
                                              uint16_t* __restrict__ Vt,
                                              const float* __restrict__ g) {
  __shared__ uint16_t smem[16896];       // As(8192)+Bs(8192); aliased tr[128][132]
  __shared__ float ssred[2][128];
  uint16_t* As = smem;
  uint16_t* Bs = smem + 8192;
  const int bid = blockIdx.x;
  int mode, lb;
  if (bid < 128)      { mode = 2; lb = bid; }
  else if (bid < 256) { mode = 1; lb = bid - 128; }
  else                { mode = 0; lb = bid - 256; }
  const uint16_t* A;
  const uint16_t* Bw;
  int nt;
  if (mode == 0)      { A = qb; Bw = Wqb; nt = 16; }
  else if (mode == 1) { A = kb; Bw = Wkb; nt = 4; }
  else                { A = vb; Bw = Wvb; nt = 4; }
  const int K = 2048;
  const int m0 = (lb / nt) << 7;
  const int n0 = (lb % nt) << 7;
  const int tid = threadIdx.x;
  const int w = tid >> 6, lane = tid & 63;
  const int wr = (w >> 1) << 6, wc = (w & 1) << 6;
  const int lr = lane & 15;
  const int g16 = ((lane >> 4) << 4);
  const int csw = ((lane & 1) << 6) | (((lane >> 1) & 1) << 5);
  f32x4 acc[4][4] = {};
  const int soff = tid * 16;
  const int scol = ((tid & 7) ^ (((tid >> 3) & 1) << 2) ^ (((tid >> 4) & 1) << 1)) << 3;
  const int srow = tid >> 3;
  for (int kt = 0; kt < K; kt += 64) {
#pragma unroll
    for (int i = 0; i < 4; ++i) {
      int off = i * 4096 + soff;
      int row = i * 32 + srow;
      async16(A + (size_t)(m0 + row) * K + kt + scol, (char*)As + off);
      async16(Bw + (size_t)(n0 + row) * K + kt + scol, (char*)Bs + off);
    }
    __syncthreads();
#pragma unroll
    for (int kk2 = 0; kk2 < 128; kk2 += 64) {
      bf16x8 af[4], bfr[4];
      const int cb = (kk2 + g16) ^ csw;
#pragma unroll
      for (int m = 0; m < 4; ++m)
        af[m] = *(const bf16x8*)((const char*)As + (wr + m * 16 + lr) * 128 + cb);
#pragma unroll
      for (int n = 0; n < 4; ++n)
        bfr[n] = *(const bf16x8*)((const char*)Bs + (wc + n * 16 + lr) * 128 + cb);
#pragma unroll
      for (int m = 0; m < 4; ++m)
#pragma unroll
        for (int n = 0; n < 4; ++n)
          acc[m][n] = __builtin_amdgcn_mfma_f32_16x16x32_bf16(af[m], bfr[n], acc[m][n], 0, 0, 0);
    }
    __syncthreads();
  }
  const int g4 = lane >> 4;
  const int r04 = g4 << 2;
  const int b = m0 >> 11;
  const int t0 = m0 & (T_ - 1);
  const int h = n0 >> 7;

  if (mode <= 1) {
    // ---- fused l2norm epilogue: rows are complete head vectors (BN=128=DK) ----
    float ss[4][4];
#pragma unroll
    for (int m = 0; m < 4; ++m)
#pragma unroll
      for (int r = 0; r < 4; ++r) {
        float s = 0.f;
#pragma unroll
        for (int n = 0; n < 4; ++n) s += acc[m][n][r] * acc[m][n][r];
        ss[m][r] = s;
      }
#pragma unroll
    for (int mask = 1; mask < 16; mask <<= 1)
#pragma unroll
      for (int m = 0; m < 4; ++m)
#pragma unroll
        for (int r = 0; r < 4; ++r) ss[m][r] += __shfl_xor(ss[m][r], mask);
#pragma unroll
    for (int m = 0; m < 4; ++m)
#pragma unroll
      for (int r = 0; r < 4; ++r)
        if (lr == (m << 2 | r)) ssred[w & 1][wr + m * 16 + g4 * 4 + r] = ss[m][r];
    __syncthreads();
    uint16_t* outp = (mode == 0) ? Qn : Kn;
    const int NHv = (mode == 0) ? H_ : KVH_;
    const float gmul = (mode == 0) ? g[h] * 0.08838834764831845f : 1.0f;  // fold 1/sqrt(128)
#pragma unroll
    for (int m = 0; m < 4; ++m)
#pragma unroll
      for (int r = 0; r < 4; ++r) {
        int row = wr + m * 16 + g4 * 4 + r;
        float tot = ssred[0][row] + ssred[1][row];
        float scl = gmul / fmaxf(sqrtf(tot), 1e-12f);
        size_t base = ((size_t)(b * NHv + h) * T_ + (t0 + row)) * 128;
#pragma unroll
        for (int n = 0; n < 4; ++n)
          outp[base + wc + n * 16 + lr] = f2bf(acc[m][n][r] * scl);
      }
  } else {
    // ---- fused transpose epilogue: write Vt (B,KVH,128,T) via LDS bounce ----
    uint16_t* tr = smem;  // stride 132 elems
#pragma unroll
    for (int m = 0; m < 4; ++m)
#pragma unroll
      for (int n = 0; n < 4; ++n)
#pragma unroll
        for (int r = 0; r < 4; ++r)
          tr[(wc + n * 16 + lr) * 132 + (wr + m * 16 + r04 + r)] = f2bf(acc[m][n][r]);
    __syncthreads();
    const int qd = tid & 3;
#pragma unroll
    for (int dd = 0; dd < 2; ++dd) {
      int d = (tid >> 2) + dd * 64;
      uint16_t* dst = Vt + ((size_t)(b * KVH_ + h) * 128 + d) * T_ + t0 + qd * 32;
      const uint16_t* srcl = &tr[d * 132 + qd * 32];
#pragma unroll
      for (int j = 0; j < 8; ++j)
        *(ushort4*)(dst + j * 4) = *(const ushort4*)(srcl + j * 4);
    }
  }
}

// ---------------- causal GQA flash attention, paired q-tiles ----------------
__global__ __launch_bounds__(256) void k_attn(const uint16_t* __restrict__ Qn,
                                              const uint16_t* __restrict__ Kn,
                                              const uint16_t* __restrict__ Vt,
                                              uint16_t* __restrict__ Y) {
  __shared__ uint16_t Ks[64 * 128];
  __shared__ uint16_t Vs[128 * 64];
  __shared__ uint16_t Ps[4 * 16 * 32];
  const int npair = T_ / 128;              // 16
  const int pair_id = blockIdx.x % npair;
  const int bh = blockIdx.x / npair;
  const int h = bh % H_;
  const int b = bh / H_;
  const int kvh = h >> 2;
  const int qtA = pair_id;                 // light tile
  const int qtB = (T_ / 64) - 1 - pair_id; // heavy tile
  const uint16_t* Qh = Qn + ((size_t)(b * H_ + h) * T_) * 128;
  const uint16_t* Kh = Kn + ((size_t)(b * KVH_ + kvh) * T_) * 128;
  const uint16_t* Vh = Vt + ((size_t)(b * KVH_ + kvh) * 128) * T_;
  const int tid = threadIdx.x;
  const int w = tid >> 6, lane = tid & 63;
  const int lr = lane & 15;
  const int lk2 = (lane >> 4) << 4;
  const int r0 = (lane >> 4) << 2;
  const int qwA = qtA * 64 + w * 16;
  const int qwB = qtB * 64 + w * 16;
  char* Psw = (char*)Ps + w * 1024;

  bf16x8 qfA[4], qfB[4];
#pragma unroll
  for (int dblk = 0; dblk < 4; ++dblk) {
    qfA[dblk] = *(const bf16x8*)&Qh[(size_t)(qwA + lr) * 128 + dblk * 32 + (lk2 >> 1)];
    qfB[dblk] = *(const bf16x8*)&Qh[(size_t)(qwB + lr) * 128 + dblk * 32 + (lk2 >> 1)];
  }
  union { uint16_t u[8]; bf16x8 v; } ou;
#pragma unroll
  for (int j = 0; j < 8; ++j) ou.u[j] = 0x3F80;
  const bf16x8 ones = ou.v;
  f32x4 oA[8] = {}, oB[8] = {};
  f32x4 sumA = {}, sumB = {};

  auto tilecompute = [&](const bf16x8* qf, f32x4* o, f32x4* sum, int qw, int kv0) {
#pragma unroll
    for (int prr = 0; prr < 2; ++prr) {
#pragma unroll
      for (int kbi = 0; kbi < 2; ++kbi) {
        int kb = prr * 2 + kbi;
        f32x4 s = {};
#pragma unroll
        for (int dblk = 0; dblk < 4; ++dblk) {
          bf16x8 kf = *(const bf16x8*)((const char*)Ks +
              ((kb * 16 + lr) << 8) + ((dblk * 64 + lk2) ^ ((lr & 7) << 4)));
          s = __builtin_amdgcn_mfma_f32_16x16x32_bf16(qf[dblk], kf, s, 0, 0, 0);
        }
        int kval = kv0 + kb * 16 + lr;
#pragma unroll
        for (int r = 0; r < 4; ++r) {
          float pv = (kval <= qw + r0 + r) ? __expf(s[r]) : 0.0f;
          *(uint16_t*)(Psw + (r0 + r) * 64 + (((kbi * 16 + lr) * 2) ^ (r << 4))) = f2bf(pv);
        }
      }
      asm volatile("s_waitcnt lgkmcnt(0)" ::: "memory");
      bf16x8 pa = *(const bf16x8*)(Psw + lr * 64 + (lk2 ^ ((lr & 3) << 4)));
#pragma unroll
      for (int dblk = 0; dblk < 8; ++dblk) {
        bf16x8 vf = *(const bf16x8*)((const char*)Vs +
            ((dblk * 16 + lr) << 7) + ((prr * 64 + lk2) ^ ((lr & 7) << 4)));
        o[dblk] = __builtin_amdgcn_mfma_f32_16x16x32_bf16(pa, vf, o[dblk], 0, 0, 0);
      }
      *sum = __builtin_amdgcn_mfma_f32_16x16x32_bf16(pa, ones, *sum, 0, 0, 0);
    }
  };

  for (int tile = 0; tile <= qtB; ++tile) {
    const int kv0 = tile * 64;
#pragma unroll
    for (int i = 0; i < 4; ++i) {
      int off = i * 4096 + tid * 16;
      int krow = off >> 8;
      int kchunk = (off >> 4) & 15;
      int kcol = (kchunk ^ (krow & 7)) << 3;
      async16(Kh + (size_t)(kv0 + krow) * 128 + kcol, (char*)Ks + off);
      int vrow = off >> 7;
      int vchunk = (off >> 4) & 7;
      int vcol = (vchunk ^ (vrow & 7)) << 3;
      async16(Vh + (size_t)vrow * T_ + kv0 + vcol, (char*)Vs + off);
    }
    __syncthreads();
    tilecompute(qfB, oB, &sumB, qwB, kv0);
    if (tile <= qtA) tilecompute(qfA, oA, &sumA, qwA, kv0);
    __syncthreads();
  }

  auto writeout = [&](const f32x4* o, const f32x4& sum, int qw) {
#pragma unroll
    for (int r = 0; r < 4; ++r) {
      float inv = 1.0f / sum[r];
      size_t base = ((size_t)b * T_ + (qw + r0 + r)) * D_ + h * 128 + lr;
#pragma unroll
      for (int dblk = 0; dblk < 8; ++dblk)
        Y[base + dblk * 16] = f2bf(o[dblk][r] * inv);
    }
  };
  writeout(oA, sumA, qwA);
  writeout(oB, sumB, qwB);
}

extern "C" void kernel_launch(void* const* d_in, const int* in_sizes, int n_in,
                              void* d_out, int out_size, void* d_ws, size_t ws_size,
                              hipStream_t stream) {
  (void)in_sizes; (void)n_in; (void)out_size; (void)ws_size;
  const float* q  = (const float*)d_in[0];
  const float* k  = (const float*)d_in[1];
  const float* v  = (const float*)d_in[2];
  const float* Wq = (const float*)d_in[3];
  const float* Wk = (const float*)d_in[4];
  const float* Wv = (const float*)d_in[5];
  const float* Wo = (const float*)d_in[6];
  const float* g  = (const float*)d_in[7];
  float* out = (float*)d_out;
  char* ws = (char*)d_ws;
  const size_t MB = 1ull << 20;
  uint16_t* qb  = (uint16_t*)(ws);             // 16MB; reused as Y after k_proj
  uint16_t* kb  = (uint16_t*)(ws + 16 * MB);   // 16MB
  uint16_t* vb  = (uint16_t*)(ws + 32 * MB);   // 16MB
  uint16_t* Wqb = (uint16_t*)(ws + 48 * MB);   // 8MB
  uint16_t* Wkb = (uint16_t*)(ws + 56 * MB);   // 2MB
  uint16_t* Wvb = (uint16_t*)(ws + 58 * MB);   // 2MB
  uint16_t* Kn  = (uint16_t*)(ws + 60 * MB);   // 4MB
  uint16_t* Vtb = (uint16_t*)(ws + 64 * MB);   // 4MB
  uint16_t* Wob = (uint16_t*)(ws + 68 * MB);   // 8MB (ws high-water: 76MB)
  uint16_t* Qn  = (uint16_t*)d_out;            // 16MB scratch in d_out; dead
                                               // before final GEMM overwrites it
  uint16_t* Y   = qb;

  // 1) convert all seven fp32 inputs in one launch
  k_cvt_all<<<17408, 256, 0, stream>>>(q, k, v, Wq, Wk, Wv, Wo,
                                       qb, kb, vb, Wqb, Wkb, Wvb, Wob);
  // 2) merged Q/K/V projection (V,K blocks first; uniform Q tail)
  k_proj<<<768, 256, 0, stream>>>(qb, kb, vb, Wqb, Wkb, Wvb, Qn, Kn, Vtb, g);
  // 3) attention (reads Qn from d_out, writes Y into qb)
  k_attn<<<B_ * H_ * (T_ / 128), 256, 0, stream>>>(Qn, Kn, Vtb, Y);
  // 4) output projection: Y * Wob^T -> fp32 out (512 blocks, 2/CU)
  k_gemm_bt<<<(B_ * T_ / 128) * (D_ / 128), 256, 0, stream>>>(Y, Wob, out, B_ * T_, D_, D_);
}